// Round 4
// baseline (1357.262 us; speedup 1.0000x reference)
//
#include <hip/hip_runtime.h>
#include <math.h>

#define N_NODES 50000
#define N_EDGES 600000
#define D 128

typedef unsigned int u32;

// ---------------------------------------------------------------------------
// Explicit zeroing (replaces unchecked hipMemsetAsync).
// ---------------------------------------------------------------------------
__global__ void zero_words(u32* __restrict__ p, long n) {
    long i = (long)blockIdx.x * blockDim.x + threadIdx.x;
    long stride = (long)gridDim.x * blockDim.x;
    for (; i < n; i += stride) p[i] = 0u;
}

// Diagnostic sentinel fill (runs only if ws_size is too small).
__global__ void fill_sentinel(float* __restrict__ p, long n, float v) {
    long i = (long)blockIdx.x * blockDim.x + threadIdx.x;
    long stride = (long)gridDim.x * blockDim.x;
    for (; i < n; i += stride) p[i] = v;
}

// ---------------------------------------------------------------------------
// Edge scatter, fp32 accumulators. One wave per edge, 2 features per lane.
// sm1[dst] += feat[src]*w ; sw1[dst] += w   (forward graph)
// sm2[src] += feat[dst]*w ; sw2[src] += w   (reverse graph)
// ---------------------------------------------------------------------------
__global__ void edge_scatter_f(const float* __restrict__ feat,
                               const int* __restrict__ esrc,
                               const int* __restrict__ edst,
                               const float* __restrict__ ew,
                               float* __restrict__ sm1, float* __restrict__ sw1,
                               float* __restrict__ sm2, float* __restrict__ sw2) {
    int lane = threadIdx.x & 63;
    int wave = (blockIdx.x * blockDim.x + threadIdx.x) >> 6;
    int nwaves = (gridDim.x * blockDim.x) >> 6;
    for (int e = wave; e < N_EDGES; e += nwaves) {
        int s = esrc[e], d = edst[e];
        float w = ew[e];
        float2 vs = *(const float2*)(feat + (size_t)s * D + lane * 2);
        float2 vd = *(const float2*)(feat + (size_t)d * D + lane * 2);
        float* o1 = sm1 + (size_t)d * D + lane * 2;
        float* o2 = sm2 + (size_t)s * D + lane * 2;
        unsafeAtomicAdd(o1 + 0, vs.x * w);
        unsafeAtomicAdd(o1 + 1, vs.y * w);
        unsafeAtomicAdd(o2 + 0, vd.x * w);
        unsafeAtomicAdd(o2 + 1, vd.y * w);
        if (lane == 0) {
            unsafeAtomicAdd(sw1 + d, w);
            unsafeAtomicAdd(sw2 + s, w);
        }
    }
}

// ---------------------------------------------------------------------------
// Divide by weight-sum in place; sanitize non-finite to 0 (diagnostic guard).
// ---------------------------------------------------------------------------
__global__ void finalize_f(float* __restrict__ sm, const float* __restrict__ sw) {
    int i = blockIdx.x * blockDim.x + threadIdx.x;  // over N*D/4 float4s
    if (i >= N_NODES * (D / 4)) return;
    int node = i >> 5;
    float s = sw[node];
    float inv = (s > 0.f) ? 1.f / s : 0.f;
    if (!isfinite(inv)) inv = 0.f;
    float4 v = ((float4*)sm)[i];
    v.x *= inv; v.y *= inv; v.z *= inv; v.w *= inv;
    if (!isfinite(v.x)) v.x = 0.f;
    if (!isfinite(v.y)) v.y = 0.f;
    if (!isfinite(v.z)) v.z = 0.f;
    if (!isfinite(v.w)) v.w = 0.f;
    ((float4*)sm)[i] = v;
}

// ---------------------------------------------------------------------------
// M1[r,k] = sum_j W_ih[r, j]     * W1[j, k]   (r<384, k<128)
// M2[r,k] = sum_j W_ih[r, 128+j] * W2[j, k]
// ---------------------------------------------------------------------------
__global__ void compute_M(const float* __restrict__ W_ih,
                          const float* __restrict__ W1,
                          const float* __restrict__ W2,
                          float* __restrict__ M1, float* __restrict__ M2) {
    int r = blockIdx.x;          // 0..383
    int k = threadIdx.x;         // 0..127
    int which = blockIdx.y;      // 0 -> M1/W1, 1 -> M2/W2
    const float* Wsel = which ? W2 : W1;
    const float* ih = W_ih + (size_t)r * (2 * D) + which * D;
    float acc = 0.f;
    for (int j = 0; j < D; ++j) acc += ih[j] * Wsel[j * D + k];
    (which ? M2 : M1)[r * D + k] = acc;
}

// ---------------------------------------------------------------------------
// Assemble B [384 x 512], col c' = c*4 + g (c real col, g gate):
//   g=0: r-gate sum  (M1 row c | M2 row c | W_hh row c)
//   g=1: z-gate sum  (rows c+128)
//   g=2: gi_n        (M1/M2 rows c+256 | 0)
//   g=3: gh_n        (0 | 0 | W_hh row c+256)
// ---------------------------------------------------------------------------
__global__ void fill_B(const float* __restrict__ M1, const float* __restrict__ M2,
                       const float* __restrict__ W_hh, float* __restrict__ Bm) {
    int idx = blockIdx.x * blockDim.x + threadIdx.x;
    if (idx >= 384 * 512) return;
    int k = idx >> 9;
    int cp = idx & 511;
    int c = cp >> 2, g = cp & 3;
    float v = 0.f;
    if (g <= 1) {
        int r = c + (g == 1 ? 128 : 0);
        v = (k < 128) ? M1[r * D + k]
          : (k < 256) ? M2[r * D + (k - 128)]
                      : W_hh[r * D + (k - 256)];
    } else if (g == 2) {
        int r = c + 256;
        v = (k < 128) ? M1[r * D + k]
          : (k < 256) ? M2[r * D + (k - 128)] : 0.f;
    } else {
        v = (k >= 256) ? W_hh[(c + 256) * D + (k - 256)] : 0.f;
    }
    if (!isfinite(v)) v = 0.f;
    Bm[idx] = v;
}

// ---------------------------------------------------------------------------
// Fused GEMM + GRU epilogue. Virtual A[i,k] (k<384): k<128 -> n1, k<256 -> n2,
// else feat. B = Bm fp32 [384 x 512] (gates interleaved in columns).
// Block: 64 nodes x 16 real cols (64 gate cols). Thread: 4 nodes x 1 real col,
// 4 gates in acc[i][0..3] -> full GRU in-register.
// ---------------------------------------------------------------------------
#define BM 64
#define BN 64
#define BK 32

__global__ __launch_bounds__(256)
void gemm_gru(const float* __restrict__ n1, const float* __restrict__ n2,
              const float* __restrict__ feat, const float* __restrict__ Bm,
              const float* __restrict__ b_ih, const float* __restrict__ b_hh,
              float* __restrict__ out) {
    __shared__ float Al[BK][BM];   // transposed A tile
    __shared__ float Bl[BK][BN];
    int tid = threadIdx.x;
    int m0 = blockIdx.x * BM;
    int c0 = blockIdx.y * 16;      // real col base; gate col base = c0*4
    int tm = tid >> 4;
    int tn = tid & 15;
    float acc[4][4] = {};

    for (int k0 = 0; k0 < 384; k0 += BK) {
        // ---- stage A: 64 nodes x 32 k, transposed into LDS ----
        {
            int node = tid >> 2;
            int gm = m0 + node;
            #pragma unroll
            for (int cc = 0; cc < 2; ++cc) {
                int chunk = (tid & 3) * 2 + cc;          // 0..7 -> 4 floats each
                float4 v = {0.f, 0.f, 0.f, 0.f};
                if (gm < N_NODES) {
                    const float* src = (k0 < 128) ? n1 : (k0 < 256) ? n2 : feat;
                    int koff = (k0 < 256) ? (k0 & 127) : (k0 - 256);
                    v = *(const float4*)(src + (size_t)gm * D + koff + chunk * 4);
                }
                Al[chunk * 4 + 0][node] = v.x;
                Al[chunk * 4 + 1][node] = v.y;
                Al[chunk * 4 + 2][node] = v.z;
                Al[chunk * 4 + 3][node] = v.w;
            }
        }
        // ---- stage B: 32 k-rows x 64 gate cols (512 float4s, 2 per thread) ----
        {
            int row = tid >> 3;                 // 0..31
            int ch  = (tid & 7) * 2;            // 0,2,..,14 -> two float4s
            const float* bsrc = Bm + (size_t)(k0 + row) * 512 + c0 * 4;
            *(float4*)&Bl[row][ch * 4]     = *(const float4*)(bsrc + ch * 4);
            *(float4*)&Bl[row][ch * 4 + 4] = *(const float4*)(bsrc + ch * 4 + 4);
        }
        __syncthreads();
        #pragma unroll
        for (int kk = 0; kk < BK; ++kk) {
            float4 a = *(const float4*)&Al[kk][tm * 4];
            float4 b = *(const float4*)&Bl[kk][tn * 4];
            float av[4] = {a.x, a.y, a.z, a.w};
            float bv[4] = {b.x, b.y, b.z, b.w};
            #pragma unroll
            for (int i = 0; i < 4; ++i)
                #pragma unroll
                for (int j = 0; j < 4; ++j)
                    acc[i][j] += av[i] * bv[j];
        }
        __syncthreads();
    }

    int c = c0 + tn;
    float bir = b_ih[c],       bhr = b_hh[c];
    float biz = b_ih[c + 128], bhz = b_hh[c + 128];
    float bin = b_ih[c + 256], bhn = b_hh[c + 256];
    #pragma unroll
    for (int i = 0; i < 4; ++i) {
        int node = m0 + tm * 4 + i;
        if (node >= N_NODES) break;
        float f = feat[(size_t)node * D + c];
        float r = 1.f / (1.f + __expf(-(acc[i][0] + bir + bhr)));
        float z = 1.f / (1.f + __expf(-(acc[i][1] + biz + bhz)));
        float ng = tanhf(acc[i][2] + bin + r * (acc[i][3] + bhn));
        out[(size_t)node * D + c] = (1.f - z) * ng + z * f;
    }
}

extern "C" void kernel_launch(void* const* d_in, const int* in_sizes, int n_in,
                              void* d_out, int out_size, void* d_ws, size_t ws_size,
                              hipStream_t stream) {
    const float* feat = (const float*)d_in[0];
    const int*   esrc = (const int*)d_in[1];
    const int*   edst = (const int*)d_in[2];
    const float* ew   = (const float*)d_in[3];
    const float* W1   = (const float*)d_in[4];
    const float* W2   = (const float*)d_in[5];
    const float* W_ih = (const float*)d_in[6];
    const float* W_hh = (const float*)d_in[7];
    const float* b_ih = (const float*)d_in[8];
    const float* b_hh = (const float*)d_in[9];
    float* out = (float*)d_out;

    const size_t ND = (size_t)N_NODES * D;
    const size_t needWords = 2 * ND + 2 * N_NODES + 2 * 384 * D + 384 * 512;
    if (ws_size < needWords * 4) {
        // Workspace too small: emit unambiguous sentinel fingerprint.
        fill_sentinel<<<512, 256, 0, stream>>>(out, (long)out_size, 12345.0f);
        return;
    }

    float* ws  = (float*)d_ws;
    float* sm1 = ws;                       // N*D
    float* sm2 = sm1 + ND;                 // N*D
    float* sw1 = sm2 + ND;                 // N
    float* sw2 = sw1 + N_NODES;            // N
    float* M1  = sw2 + N_NODES;            // 384*128
    float* M2  = M1 + 384 * D;             // 384*128
    float* Bm  = M2 + 384 * D;             // 384*512

    zero_words<<<2048, 256, 0, stream>>>((u32*)d_ws, (long)(2 * ND + 2 * N_NODES));
    edge_scatter_f<<<4096, 256, 0, stream>>>(feat, esrc, edst, ew, sm1, sw1, sm2, sw2);
    finalize_f<<<(N_NODES * (D / 4) + 255) / 256, 256, 0, stream>>>(sm1, sw1);
    finalize_f<<<(N_NODES * (D / 4) + 255) / 256, 256, 0, stream>>>(sm2, sw2);
    compute_M<<<dim3(384, 2), 128, 0, stream>>>(W_ih, W1, W2, M1, M2);
    fill_B<<<(384 * 512 + 255) / 256, 256, 0, stream>>>(M1, M2, W_hh, Bm);
    gemm_gru<<<dim3((N_NODES + BM - 1) / BM, D / 16), 256, 0, stream>>>(
        sm1, sm2, feat, Bm, b_ih, b_hh, out);
}

// Round 5
// 767.787 us; speedup vs baseline: 1.7678x; 1.7678x over previous
//
#include <hip/hip_runtime.h>
#include <math.h>

#define N_NODES 50000
#define N_EDGES 600000
#define D 128

typedef unsigned int u32;

// ---------------------------------------------------------------------------
// Utility: explicit zero / sentinel.
// ---------------------------------------------------------------------------
__global__ void zero_words(u32* __restrict__ p, long n) {
    long i = (long)blockIdx.x * blockDim.x + threadIdx.x;
    long stride = (long)gridDim.x * blockDim.x;
    for (; i < n; i += stride) p[i] = 0u;
}

__global__ void fill_sentinel(float* __restrict__ p, long n, float v) {
    long i = (long)blockIdx.x * blockDim.x + threadIdx.x;
    long stride = (long)gridDim.x * blockDim.x;
    for (; i < n; i += stride) p[i] = v;
}

// ===========================================================================
// CSR build: count -> exclusive scan (single block) -> scatter edge ids.
// ===========================================================================
__global__ void count_deg(const int* __restrict__ key, int* __restrict__ cnt) {
    int e = blockIdx.x * blockDim.x + threadIdx.x;
    if (e < N_EDGES) atomicAdd(&cnt[key[e]], 1);
}

// Single-workgroup in-place exclusive scan over n ints.
__global__ void exscan_block(int* __restrict__ a, int n) {
    __shared__ int part[1024];
    int t = threadIdx.x;
    int chunk = (n + 1023) / 1024;
    int lo = t * chunk;
    int hi = min(lo + chunk, n);
    int s = 0;
    for (int i = lo; i < hi; ++i) s += a[i];
    part[t] = s;
    __syncthreads();
    for (int d = 1; d < 1024; d <<= 1) {
        int v = (t >= d) ? part[t - d] : 0;
        __syncthreads();
        part[t] += v;
        __syncthreads();
    }
    int base = (t == 0) ? 0 : part[t - 1];
    for (int i = lo; i < hi; ++i) { int v = a[i]; a[i] = base; base += v; }
}

// After this, off[n] = end(n); start(n) = (n==0) ? 0 : off[n-1].
__global__ void scatter_eid(const int* __restrict__ key, int* __restrict__ off,
                            int* __restrict__ eid) {
    int e = blockIdx.x * blockDim.x + threadIdx.x;
    if (e < N_EDGES) {
        int p = atomicAdd(&off[key[e]], 1);
        eid[p] = e;
    }
}

// ---------------------------------------------------------------------------
// Gather-aggregate: one wave per node; lane handles 2 features. Mean fused.
// ---------------------------------------------------------------------------
__global__ void gather_agg(const float* __restrict__ feat,
                           const int* __restrict__ srcidx,
                           const float* __restrict__ ew,
                           const int* __restrict__ off,
                           const int* __restrict__ eid,
                           float* __restrict__ sm) {
    int wave = (blockIdx.x * blockDim.x + threadIdx.x) >> 6;
    int lane = threadIdx.x & 63;
    if (wave >= N_NODES) return;
    int n = wave;
    int start = (n == 0) ? 0 : off[n - 1];
    int end = off[n];
    float ax = 0.f, ay = 0.f, sumw = 0.f;
    for (int p = start; p < end; ++p) {
        int e = eid[p];
        int s = srcidx[e];
        float w = ew[e];
        float2 v = *(const float2*)(feat + (size_t)s * D + lane * 2);
        ax += v.x * w;
        ay += v.y * w;
        sumw += w;
    }
    float inv = (sumw > 0.f) ? 1.f / sumw : 0.f;
    if (!isfinite(inv)) inv = 0.f;
    float2 o; o.x = ax * inv; o.y = ay * inv;
    *(float2*)(sm + (size_t)n * D + lane * 2) = o;
}

// ===========================================================================
// Fallback: atomic scatter path (round-4 proven), used only if ws too small.
// ===========================================================================
__global__ void edge_scatter_f(const float* __restrict__ feat,
                               const int* __restrict__ esrc,
                               const int* __restrict__ edst,
                               const float* __restrict__ ew,
                               float* __restrict__ sm1, float* __restrict__ sw1,
                               float* __restrict__ sm2, float* __restrict__ sw2) {
    int lane = threadIdx.x & 63;
    int wave = (blockIdx.x * blockDim.x + threadIdx.x) >> 6;
    int nwaves = (gridDim.x * blockDim.x) >> 6;
    for (int e = wave; e < N_EDGES; e += nwaves) {
        int s = esrc[e], d = edst[e];
        float w = ew[e];
        float2 vs = *(const float2*)(feat + (size_t)s * D + lane * 2);
        float2 vd = *(const float2*)(feat + (size_t)d * D + lane * 2);
        float* o1 = sm1 + (size_t)d * D + lane * 2;
        float* o2 = sm2 + (size_t)s * D + lane * 2;
        unsafeAtomicAdd(o1 + 0, vs.x * w);
        unsafeAtomicAdd(o1 + 1, vs.y * w);
        unsafeAtomicAdd(o2 + 0, vd.x * w);
        unsafeAtomicAdd(o2 + 1, vd.y * w);
        if (lane == 0) {
            unsafeAtomicAdd(sw1 + d, w);
            unsafeAtomicAdd(sw2 + s, w);
        }
    }
}

__global__ void finalize_f(float* __restrict__ sm, const float* __restrict__ sw) {
    int i = blockIdx.x * blockDim.x + threadIdx.x;
    if (i >= N_NODES * (D / 4)) return;
    int node = i >> 5;
    float s = sw[node];
    float inv = (s > 0.f) ? 1.f / s : 0.f;
    if (!isfinite(inv)) inv = 0.f;
    float4 v = ((float4*)sm)[i];
    v.x *= inv; v.y *= inv; v.z *= inv; v.w *= inv;
    if (!isfinite(v.x)) v.x = 0.f;
    if (!isfinite(v.y)) v.y = 0.f;
    if (!isfinite(v.z)) v.z = 0.f;
    if (!isfinite(v.w)) v.w = 0.f;
    ((float4*)sm)[i] = v;
}

// ===========================================================================
// Weight folding: M1 = W_ih[:, :128] @ W1 ; M2 = W_ih[:, 128:] @ W2.
// ===========================================================================
__global__ void compute_M(const float* __restrict__ W_ih,
                          const float* __restrict__ W1,
                          const float* __restrict__ W2,
                          float* __restrict__ M1, float* __restrict__ M2) {
    int r = blockIdx.x;          // 0..383
    int k = threadIdx.x;         // 0..127
    int which = blockIdx.y;
    const float* Wsel = which ? W2 : W1;
    const float* ih = W_ih + (size_t)r * (2 * D) + which * D;
    float acc = 0.f;
    for (int j = 0; j < D; ++j) acc += ih[j] * Wsel[j * D + k];
    (which ? M2 : M1)[r * D + k] = acc;
}

// B [384 x 512], col c' = c*4 + g (gates interleaved: r-sum, z-sum, gi_n, gh_n).
__global__ void fill_B(const float* __restrict__ M1, const float* __restrict__ M2,
                       const float* __restrict__ W_hh, float* __restrict__ Bm) {
    int idx = blockIdx.x * blockDim.x + threadIdx.x;
    if (idx >= 384 * 512) return;
    int k = idx >> 9;
    int cp = idx & 511;
    int c = cp >> 2, g = cp & 3;
    float v = 0.f;
    if (g <= 1) {
        int r = c + (g == 1 ? 128 : 0);
        v = (k < 128) ? M1[r * D + k]
          : (k < 256) ? M2[r * D + (k - 128)]
                      : W_hh[r * D + (k - 256)];
    } else if (g == 2) {
        int r = c + 256;
        v = (k < 128) ? M1[r * D + k]
          : (k < 256) ? M2[r * D + (k - 128)] : 0.f;
    } else {
        v = (k >= 256) ? W_hh[(c + 256) * D + (k - 256)] : 0.f;
    }
    if (!isfinite(v)) v = 0.f;
    Bm[idx] = v;
}

// ===========================================================================
// Fused GEMM + GRU epilogue (unchanged from round 4).
// ===========================================================================
#define BM 64
#define BN 64
#define BK 32

__global__ __launch_bounds__(256)
void gemm_gru(const float* __restrict__ n1, const float* __restrict__ n2,
              const float* __restrict__ feat, const float* __restrict__ Bm,
              const float* __restrict__ b_ih, const float* __restrict__ b_hh,
              float* __restrict__ out) {
    __shared__ float Al[BK][BM];
    __shared__ float Bl[BK][BN];
    int tid = threadIdx.x;
    int m0 = blockIdx.x * BM;
    int c0 = blockIdx.y * 16;
    int tm = tid >> 4;
    int tn = tid & 15;
    float acc[4][4] = {};

    for (int k0 = 0; k0 < 384; k0 += BK) {
        {
            int node = tid >> 2;
            int gm = m0 + node;
            #pragma unroll
            for (int cc = 0; cc < 2; ++cc) {
                int chunk = (tid & 3) * 2 + cc;
                float4 v = {0.f, 0.f, 0.f, 0.f};
                if (gm < N_NODES) {
                    const float* src = (k0 < 128) ? n1 : (k0 < 256) ? n2 : feat;
                    int koff = (k0 < 256) ? (k0 & 127) : (k0 - 256);
                    v = *(const float4*)(src + (size_t)gm * D + koff + chunk * 4);
                }
                Al[chunk * 4 + 0][node] = v.x;
                Al[chunk * 4 + 1][node] = v.y;
                Al[chunk * 4 + 2][node] = v.z;
                Al[chunk * 4 + 3][node] = v.w;
            }
        }
        {
            int row = tid >> 3;
            int ch  = (tid & 7) * 2;
            const float* bsrc = Bm + (size_t)(k0 + row) * 512 + c0 * 4;
            *(float4*)&Bl[row][ch * 4]     = *(const float4*)(bsrc + ch * 4);
            *(float4*)&Bl[row][ch * 4 + 4] = *(const float4*)(bsrc + ch * 4 + 4);
        }
        __syncthreads();
        #pragma unroll
        for (int kk = 0; kk < BK; ++kk) {
            float4 a = *(const float4*)&Al[kk][tm * 4];
            float4 b = *(const float4*)&Bl[kk][tn * 4];
            float av[4] = {a.x, a.y, a.z, a.w};
            float bv[4] = {b.x, b.y, b.z, b.w};
            #pragma unroll
            for (int i = 0; i < 4; ++i)
                #pragma unroll
                for (int j = 0; j < 4; ++j)
                    acc[i][j] += av[i] * bv[j];
        }
        __syncthreads();
    }

    int c = c0 + tn;
    float bir = b_ih[c],       bhr = b_hh[c];
    float biz = b_ih[c + 128], bhz = b_hh[c + 128];
    float bin = b_ih[c + 256], bhn = b_hh[c + 256];
    #pragma unroll
    for (int i = 0; i < 4; ++i) {
        int node = m0 + tm * 4 + i;
        if (node >= N_NODES) break;
        float f = feat[(size_t)node * D + c];
        float r = 1.f / (1.f + __expf(-(acc[i][0] + bir + bhr)));
        float z = 1.f / (1.f + __expf(-(acc[i][1] + biz + bhz)));
        float ng = tanhf(acc[i][2] + bin + r * (acc[i][3] + bhn));
        out[(size_t)node * D + c] = (1.f - z) * ng + z * f;
    }
}

// ===========================================================================
extern "C" void kernel_launch(void* const* d_in, const int* in_sizes, int n_in,
                              void* d_out, int out_size, void* d_ws, size_t ws_size,
                              hipStream_t stream) {
    const float* feat = (const float*)d_in[0];
    const int*   esrc = (const int*)d_in[1];
    const int*   edst = (const int*)d_in[2];
    const float* ew   = (const float*)d_in[3];
    const float* W1   = (const float*)d_in[4];
    const float* W2   = (const float*)d_in[5];
    const float* W_ih = (const float*)d_in[6];
    const float* W_hh = (const float*)d_in[7];
    const float* b_ih = (const float*)d_in[8];
    const float* b_hh = (const float*)d_in[9];
    float* out = (float*)d_out;

    const size_t ND = (size_t)N_NODES * D;
    const size_t wM = 2 * (size_t)384 * D + (size_t)384 * 512;      // M1,M2,Bm
    const size_t needCSR   = (2 * ND + N_NODES + N_EDGES + wM) * 4; // ~55.0 MB
    const size_t needAtomic= (2 * ND + 2 * N_NODES + wM) * 4;       // ~52.8 MB

    const int EB = (N_EDGES + 255) / 256;          // edge-parallel grid
    const int NB = (N_NODES + 255) / 256;

    if (ws_size >= needCSR) {
        // ---------------- CSR gather path ----------------
        float* sm1 = (float*)d_ws;            // ND
        float* sm2 = sm1 + ND;                // ND
        int*   off = (int*)(sm2 + ND);        // N
        int*   eid = off + N_NODES;           // E
        float* M1  = (float*)(eid + N_EDGES); // 384*128
        float* M2  = M1 + 384 * D;            // 384*128
        float* Bm  = M2 + 384 * D;            // 384*512

        // direction 1: key = dst, gather feat[src] -> sm1
        zero_words<<<NB, 256, 0, stream>>>((u32*)off, N_NODES);
        count_deg<<<EB, 256, 0, stream>>>(edst, off);
        exscan_block<<<1, 1024, 0, stream>>>(off, N_NODES);
        scatter_eid<<<EB, 256, 0, stream>>>(edst, off, eid);
        gather_agg<<<(N_NODES * 64 + 255) / 256, 256, 0, stream>>>(
            feat, esrc, ew, off, eid, sm1);

        // direction 2: key = src, gather feat[dst] -> sm2
        zero_words<<<NB, 256, 0, stream>>>((u32*)off, N_NODES);
        count_deg<<<EB, 256, 0, stream>>>(esrc, off);
        exscan_block<<<1, 1024, 0, stream>>>(off, N_NODES);
        scatter_eid<<<EB, 256, 0, stream>>>(esrc, off, eid);
        gather_agg<<<(N_NODES * 64 + 255) / 256, 256, 0, stream>>>(
            feat, edst, ew, off, eid, sm2);

        compute_M<<<dim3(384, 2), 128, 0, stream>>>(W_ih, W1, W2, M1, M2);
        fill_B<<<(384 * 512 + 255) / 256, 256, 0, stream>>>(M1, M2, W_hh, Bm);
        gemm_gru<<<dim3((N_NODES + BM - 1) / BM, D / 16), 256, 0, stream>>>(
            sm1, sm2, feat, Bm, b_ih, b_hh, out);
    } else if (ws_size >= needAtomic) {
        // ---------------- atomic fallback (round-4 proven) ----------------
        float* ws  = (float*)d_ws;
        float* sm1 = ws;
        float* sm2 = sm1 + ND;
        float* sw1 = sm2 + ND;
        float* sw2 = sw1 + N_NODES;
        float* M1  = sw2 + N_NODES;
        float* M2  = M1 + 384 * D;
        float* Bm  = M2 + 384 * D;

        zero_words<<<2048, 256, 0, stream>>>((u32*)d_ws, (long)(2 * ND + 2 * N_NODES));
        edge_scatter_f<<<4096, 256, 0, stream>>>(feat, esrc, edst, ew, sm1, sw1, sm2, sw2);
        finalize_f<<<(N_NODES * (D / 4) + 255) / 256, 256, 0, stream>>>(sm1, sw1);
        finalize_f<<<(N_NODES * (D / 4) + 255) / 256, 256, 0, stream>>>(sm2, sw2);
        compute_M<<<dim3(384, 2), 128, 0, stream>>>(W_ih, W1, W2, M1, M2);
        fill_B<<<(384 * 512 + 255) / 256, 256, 0, stream>>>(M1, M2, W_hh, Bm);
        gemm_gru<<<dim3((N_NODES + BM - 1) / BM, D / 16), 256, 0, stream>>>(
            sm1, sm2, feat, Bm, b_ih, b_hh, out);
    } else {
        fill_sentinel<<<512, 256, 0, stream>>>(out, (long)out_size, 12345.0f);
    }
}

// Round 6
// 566.704 us; speedup vs baseline: 2.3950x; 1.3548x over previous
//
#include <hip/hip_runtime.h>
#include <math.h>

#define N_NODES 50000
#define N_EDGES 600000
#define D 128
#define KTOT 384    // 3*D  (k: [n1 | n2 | feat])
#define NCOLS 512   // 4*D  (gate-interleaved cols: c' = 4c+g)

typedef unsigned int u32;
typedef unsigned short u16;

typedef __attribute__((ext_vector_type(8))) short bf16x8;   // 8 bf16 (4 VGPRs)
typedef __attribute__((ext_vector_type(4))) float f32x4;

__device__ __forceinline__ float b2f(u16 x) {
    u32 u = ((u32)x) << 16;
    float f; __builtin_memcpy(&f, &u, 4);
    return f;
}
__device__ __forceinline__ u16 f2b(float f) {   // RNE bf16
    u32 u; __builtin_memcpy(&u, &f, 4);
    u32 r = (u + 0x7fffu + ((u >> 16) & 1u)) >> 16;
    return (u16)r;
}

// ---------------------------------------------------------------------------
__global__ void zero_words(u32* __restrict__ p, long n) {
    long i = (long)blockIdx.x * blockDim.x + threadIdx.x;
    long stride = (long)gridDim.x * blockDim.x;
    for (; i < n; i += stride) p[i] = 0u;
}

__global__ void fill_sentinel(float* __restrict__ p, long n, float v) {
    long i = (long)blockIdx.x * blockDim.x + threadIdx.x;
    long stride = (long)gridDim.x * blockDim.x;
    for (; i < n; i += stride) p[i] = v;
}

// ---------------------------------------------------------------------------
// feat fp32 -> bf16 into Ah[:, 256:384]
// ---------------------------------------------------------------------------
__global__ void convert_feat(const float* __restrict__ feat, u16* __restrict__ Ah) {
    int i = blockIdx.x * blockDim.x + threadIdx.x;   // over N*D/4
    if (i >= N_NODES * (D / 4)) return;
    int n = i >> 5, j4 = i & 31;
    float4 v = *(const float4*)(feat + (size_t)n * D + j4 * 4);
    ushort4 o;
    o.x = f2b(v.x); o.y = f2b(v.y); o.z = f2b(v.z); o.w = f2b(v.w);
    *(ushort4*)(Ah + (size_t)n * KTOT + 256 + j4 * 4) = o;
}

// ---------------------------------------------------------------------------
// CSR build: count -> single-block exclusive scan -> scatter edge ids.
// ---------------------------------------------------------------------------
__global__ void count_deg(const int* __restrict__ key, int* __restrict__ cnt) {
    int e = blockIdx.x * blockDim.x + threadIdx.x;
    if (e < N_EDGES) atomicAdd(&cnt[key[e]], 1);
}

__global__ void exscan_block(int* __restrict__ a, int n) {
    __shared__ int part[1024];
    int t = threadIdx.x;
    int chunk = (n + 1023) / 1024;
    int lo = t * chunk;
    int hi = min(lo + chunk, n);
    int s = 0;
    for (int i = lo; i < hi; ++i) s += a[i];
    part[t] = s;
    __syncthreads();
    for (int d = 1; d < 1024; d <<= 1) {
        int v = (t >= d) ? part[t - d] : 0;
        __syncthreads();
        part[t] += v;
        __syncthreads();
    }
    int base = (t == 0) ? 0 : part[t - 1];
    for (int i = lo; i < hi; ++i) { int v = a[i]; a[i] = base; base += v; }
}

// After this, off[n] = end(n); start(n) = (n==0) ? 0 : off[n-1].
__global__ void scatter_eid(const int* __restrict__ key, int* __restrict__ off,
                            int* __restrict__ eid) {
    int e = blockIdx.x * blockDim.x + threadIdx.x;
    if (e < N_EDGES) {
        int p = atomicAdd(&off[key[e]], 1);
        eid[p] = e;
    }
}

// ---------------------------------------------------------------------------
// Gather-aggregate (bf16 in/out): one wave per node, 2 features per lane.
// Reads bf16 feat from Ah[:,256:384]; writes mean into Ah[:, dstoff:dstoff+128].
// ---------------------------------------------------------------------------
__global__ void gather_agg_h(u16* __restrict__ Ah,
                             const int* __restrict__ srcidx,
                             const float* __restrict__ ew,
                             const int* __restrict__ off,
                             const int* __restrict__ eid,
                             int dstoff) {
    int wave = (blockIdx.x * blockDim.x + threadIdx.x) >> 6;
    int lane = threadIdx.x & 63;
    if (wave >= N_NODES) return;
    int start = (wave == 0) ? 0 : off[wave - 1];
    int end = off[wave];
    float ax = 0.f, ay = 0.f, sw = 0.f;
    for (int p = start; p < end; ++p) {
        int e = eid[p];
        int s = srcidx[e];
        float w = ew[e];
        u32 v = *(const u32*)(Ah + (size_t)s * KTOT + 256 + lane * 2);
        ax += b2f((u16)v) * w;
        ay += b2f((u16)(v >> 16)) * w;
        sw += w;
    }
    float inv = (sw > 0.f) ? 1.f / sw : 0.f;
    if (!isfinite(inv)) inv = 0.f;
    u32 o = ((u32)f2b(ay * inv) << 16) | (u32)f2b(ax * inv);
    *(u32*)(Ah + (size_t)wave * KTOT + dstoff + lane * 2) = o;
}

// ---------------------------------------------------------------------------
// Weight folding: M1 = W_ih[:, :128] @ W1 ; M2 = W_ih[:, 128:] @ W2 (fp32).
// ---------------------------------------------------------------------------
__global__ void compute_M(const float* __restrict__ W_ih,
                          const float* __restrict__ W1,
                          const float* __restrict__ W2,
                          float* __restrict__ M1, float* __restrict__ M2) {
    int r = blockIdx.x;          // 0..383
    int k = threadIdx.x;         // 0..127
    int which = blockIdx.y;
    const float* Wsel = which ? W2 : W1;
    const float* ih = W_ih + (size_t)r * (2 * D) + which * D;
    float acc = 0.f;
    for (int j = 0; j < D; ++j) acc += ih[j] * Wsel[j * D + k];
    (which ? M2 : M1)[r * D + k] = acc;
}

// ---------------------------------------------------------------------------
// Bt [512 cols][384 k] bf16, k-contiguous rows. Col c' = 4c+g:
//   g=0: r-sum rows c      (M1 | M2 | W_hh)
//   g=1: z-sum rows c+128
//   g=2: gi_n  rows c+256  (M1 | M2 | 0)
//   g=3: gh_n              (0 | 0 | W_hh row c+256)
// ---------------------------------------------------------------------------
__global__ void fill_Bt(const float* __restrict__ M1, const float* __restrict__ M2,
                        const float* __restrict__ W_hh, u16* __restrict__ Bt) {
    int idx = blockIdx.x * blockDim.x + threadIdx.x;
    if (idx >= NCOLS * KTOT) return;
    int cp = idx / KTOT;
    int k  = idx - cp * KTOT;
    int c = cp >> 2, g = cp & 3;
    float v = 0.f;
    if (g <= 1) {
        int r = c + (g == 1 ? 128 : 0);
        v = (k < 128) ? M1[r * D + k]
          : (k < 256) ? M2[r * D + (k - 128)]
                      : W_hh[r * D + (k - 256)];
    } else if (g == 2) {
        int r = c + 256;
        v = (k < 128) ? M1[r * D + k]
          : (k < 256) ? M2[r * D + (k - 128)] : 0.f;
    } else {
        v = (k >= 256) ? W_hh[(c + 256) * D + (k - 256)] : 0.f;
    }
    if (!isfinite(v)) v = 0.f;
    Bt[idx] = f2b(v);
}

// ---------------------------------------------------------------------------
// MFMA GEMM + fused GRU. Block 128x128 (2x2 waves of 64x64), K=384.
// Fragments loaded directly from global (A reused 4x; Bt is L2-resident).
// mfma_f32_16x16x32_bf16: A lane: row=l&15, k=(l>>4)*8+j (16B contig).
//                          C/D:   col=l&15, row=(l>>4)*4+reg   [m89]
// Gate de-interleave via per-wave LDS transpose, then GRU in-register.
// ---------------------------------------------------------------------------
__global__ __launch_bounds__(256)
void gemm_gru_mfma(const u16* __restrict__ Ah, const u16* __restrict__ Bt,
                   const float* __restrict__ feat,
                   const float* __restrict__ b_ih, const float* __restrict__ b_hh,
                   float* __restrict__ out) {
    __shared__ float epi[4][16][65];
    int tid = threadIdx.x, lane = tid & 63, wid = tid >> 6;
    int wm = wid >> 1, wn = wid & 1;
    int mw = blockIdx.y * 128 + wm * 64;    // wave row (node) base
    int nw = blockIdx.x * 128 + wn * 64;    // wave gate-col base
    int rif = lane & 15, kg = lane >> 4;

    f32x4 acc[4][4];
    #pragma unroll
    for (int i = 0; i < 4; ++i)
        #pragma unroll
        for (int j = 0; j < 4; ++j)
            acc[i][j] = (f32x4){0.f, 0.f, 0.f, 0.f};

    int arow[4];
    #pragma unroll
    for (int mf = 0; mf < 4; ++mf)
        arow[mf] = min(mw + mf * 16 + rif, N_NODES - 1);

    for (int k0 = 0; k0 < KTOT; k0 += 32) {
        bf16x8 a[4], b[4];
        #pragma unroll
        for (int mf = 0; mf < 4; ++mf)
            a[mf] = *(const bf16x8*)(Ah + (size_t)arow[mf] * KTOT + k0 + kg * 8);
        #pragma unroll
        for (int nf = 0; nf < 4; ++nf)
            b[nf] = *(const bf16x8*)(Bt + (size_t)(nw + nf * 16 + rif) * KTOT + k0 + kg * 8);
        #pragma unroll
        for (int mf = 0; mf < 4; ++mf)
            #pragma unroll
            for (int nf = 0; nf < 4; ++nf)
                acc[mf][nf] = __builtin_amdgcn_mfma_f32_16x16x32_bf16(
                    a[mf], b[nf], acc[mf][nf], 0, 0, 0);
    }

    // ---- epilogue: de-interleave gates + GRU ----
    int rc0 = nw >> 2;          // wave real-col base (16 real cols)
    int erow = lane >> 2;       // 0..15: row handled in read phase
    int g4 = lane & 3;          // 4 real cols per lane
    int cbase = rc0 + g4 * 4;
    float4 bi_r = *(const float4*)(b_ih + cbase);
    float4 bh_r = *(const float4*)(b_hh + cbase);
    float4 bi_z = *(const float4*)(b_ih + cbase + 128);
    float4 bh_z = *(const float4*)(b_hh + cbase + 128);
    float4 bi_n = *(const float4*)(b_ih + cbase + 256);
    float4 bh_n = *(const float4*)(b_hh + cbase + 256);

    #pragma unroll
    for (int mf = 0; mf < 4; ++mf) {
        __syncthreads();    // region reuse fence (uniform)
        #pragma unroll
        for (int nf = 0; nf < 4; ++nf)
            #pragma unroll
            for (int reg = 0; reg < 4; ++reg)
                epi[wid][kg * 4 + reg][nf * 16 + rif] = acc[mf][nf][reg];
        __syncthreads();

        float4 q0 = *(const float4*)&epi[wid][erow][g4 * 16 + 0];
        float4 q1 = *(const float4*)&epi[wid][erow][g4 * 16 + 4];
        float4 q2 = *(const float4*)&epi[wid][erow][g4 * 16 + 8];
        float4 q3 = *(const float4*)&epi[wid][erow][g4 * 16 + 12];

        int node = mw + mf * 16 + erow;
        if (node < N_NODES) {
            float4 f = *(const float4*)(feat + (size_t)node * D + cbase);
            float4 res;
            {
                float r = 1.f / (1.f + __expf(-(q0.x + bi_r.x + bh_r.x)));
                float z = 1.f / (1.f + __expf(-(q0.y + bi_z.x + bh_z.x)));
                float ng = tanhf(q0.z + bi_n.x + r * (q0.w + bh_n.x));
                res.x = (1.f - z) * ng + z * f.x;
            }
            {
                float r = 1.f / (1.f + __expf(-(q1.x + bi_r.y + bh_r.y)));
                float z = 1.f / (1.f + __expf(-(q1.y + bi_z.y + bh_z.y)));
                float ng = tanhf(q1.z + bi_n.y + r * (q1.w + bh_n.y));
                res.y = (1.f - z) * ng + z * f.y;
            }
            {
                float r = 1.f / (1.f + __expf(-(q2.x + bi_r.z + bh_r.z)));
                float z = 1.f / (1.f + __expf(-(q2.y + bi_z.z + bh_z.z)));
                float ng = tanhf(q2.z + bi_n.z + r * (q2.w + bh_n.z));
                res.z = (1.f - z) * ng + z * f.z;
            }
            {
                float r = 1.f / (1.f + __expf(-(q3.x + bi_r.w + bh_r.w)));
                float z = 1.f / (1.f + __expf(-(q3.y + bi_z.w + bh_z.w)));
                float ng = tanhf(q3.z + bi_n.w + r * (q3.w + bh_n.w));
                res.w = (1.f - z) * ng + z * f.w;
            }
            *(float4*)(out + (size_t)node * D + cbase) = res;
        }
    }
}

// ===========================================================================
extern "C" void kernel_launch(void* const* d_in, const int* in_sizes, int n_in,
                              void* d_out, int out_size, void* d_ws, size_t ws_size,
                              hipStream_t stream) {
    const float* feat = (const float*)d_in[0];
    const int*   esrc = (const int*)d_in[1];
    const int*   edst = (const int*)d_in[2];
    const float* ew   = (const float*)d_in[3];
    const float* W1   = (const float*)d_in[4];
    const float* W2   = (const float*)d_in[5];
    const float* W_ih = (const float*)d_in[6];
    const float* W_hh = (const float*)d_in[7];
    const float* b_ih = (const float*)d_in[8];
    const float* b_hh = (const float*)d_in[9];
    float* out = (float*)d_out;

    // ws layout (words): Ah 9.6M | off 50K | eid 600K | M1 49152 | M2 49152 | Bt 98304
    const size_t AH_ELEMS = (size_t)N_NODES * KTOT;             // u16 count
    const size_t needWords = AH_ELEMS / 2 + N_NODES + N_EDGES
                           + 2 * (size_t)KTOT * D + (NCOLS * KTOT) / 2;
    if (ws_size < needWords * 4) {
        fill_sentinel<<<512, 256, 0, stream>>>(out, (long)out_size, 12345.0f);
        return;
    }

    u16*   Ah  = (u16*)d_ws;
    int*   off = (int*)(Ah + AH_ELEMS);
    int*   eid = off + N_NODES;
    float* M1  = (float*)(eid + N_EDGES);
    float* M2  = M1 + KTOT * D;
    u16*   Bt  = (u16*)(M2 + KTOT * D);

    const int EB = (N_EDGES + 255) / 256;
    const int NB = (N_NODES + 255) / 256;
    const int GB = (N_NODES * 64 + 255) / 256;

    convert_feat<<<(N_NODES * (D / 4) + 255) / 256, 256, 0, stream>>>(feat, Ah);

    // direction 1: key = dst, gather feat[src] -> Ah[:, 0:128]
    zero_words<<<NB, 256, 0, stream>>>((u32*)off, N_NODES);
    count_deg<<<EB, 256, 0, stream>>>(edst, off);
    exscan_block<<<1, 1024, 0, stream>>>(off, N_NODES);
    scatter_eid<<<EB, 256, 0, stream>>>(edst, off, eid);
    gather_agg_h<<<GB, 256, 0, stream>>>(Ah, esrc, ew, off, eid, 0);

    // direction 2: key = src, gather feat[dst] -> Ah[:, 128:256]
    zero_words<<<NB, 256, 0, stream>>>((u32*)off, N_NODES);
    count_deg<<<EB, 256, 0, stream>>>(esrc, off);
    exscan_block<<<1, 1024, 0, stream>>>(off, N_NODES);
    scatter_eid<<<EB, 256, 0, stream>>>(esrc, off, eid);
    gather_agg_h<<<GB, 256, 0, stream>>>(Ah, edst, ew, off, eid, 128);

    compute_M<<<dim3(KTOT, 2), 128, 0, stream>>>(W_ih, W1, W2, M1, M2);
    fill_Bt<<<(NCOLS * KTOT + 255) / 256, 256, 0, stream>>>(M1, M2, W_hh, Bt);

    gemm_gru_mfma<<<dim3(NCOLS / 128, (N_NODES + 127) / 128), 256, 0, stream>>>(
        Ah, Bt, feat, b_ih, b_hh, out);
}

// Round 7
// 397.360 us; speedup vs baseline: 3.4157x; 1.4262x over previous
//
#include <hip/hip_runtime.h>
#include <math.h>

#define N_NODES 50000
#define N_EDGES 600000
#define D 128
#define KTOT 384    // 3*D  (k: [n1 | n2 | feat])
#define NCOLS 512   // 4*D  (gate-interleaved cols: c' = 4c+g)

typedef unsigned int u32;
typedef unsigned short u16;

typedef __attribute__((ext_vector_type(8))) short bf16x8;   // 8 bf16 (4 VGPRs)
typedef __attribute__((ext_vector_type(4))) float f32x4;

__device__ __forceinline__ float b2f(u16 x) {
    u32 u = ((u32)x) << 16;
    float f; __builtin_memcpy(&f, &u, 4);
    return f;
}
__device__ __forceinline__ u16 f2b(float f) {   // RNE bf16
    u32 u; __builtin_memcpy(&u, &f, 4);
    u32 r = (u + 0x7fffu + ((u >> 16) & 1u)) >> 16;
    return (u16)r;
}

// ---------------------------------------------------------------------------
__global__ void zero_words(u32* __restrict__ p, long n) {
    long i = (long)blockIdx.x * blockDim.x + threadIdx.x;
    long stride = (long)gridDim.x * blockDim.x;
    for (; i < n; i += stride) p[i] = 0u;
}

__global__ void fill_sentinel(float* __restrict__ p, long n, float v) {
    long i = (long)blockIdx.x * blockDim.x + threadIdx.x;
    long stride = (long)gridDim.x * blockDim.x;
    for (; i < n; i += stride) p[i] = v;
}

// ---------------------------------------------------------------------------
// feat fp32 -> bf16 into Ah[:, 256:384]
// ---------------------------------------------------------------------------
__global__ void convert_feat(const float* __restrict__ feat, u16* __restrict__ Ah) {
    int i = blockIdx.x * blockDim.x + threadIdx.x;   // over N*D/4
    if (i >= N_NODES * (D / 4)) return;
    int n = i >> 5, j4 = i & 31;
    float4 v = *(const float4*)(feat + (size_t)n * D + j4 * 4);
    ushort4 o;
    o.x = f2b(v.x); o.y = f2b(v.y); o.z = f2b(v.z); o.w = f2b(v.w);
    *(ushort4*)(Ah + (size_t)n * KTOT + 256 + j4 * 4) = o;
}

// ---------------------------------------------------------------------------
// CSR build, both directions fused.
// ---------------------------------------------------------------------------
__global__ void count_both(const int* __restrict__ esrc, const int* __restrict__ edst,
                           int* __restrict__ cnt1, int* __restrict__ cnt2) {
    int e = blockIdx.x * blockDim.x + threadIdx.x;
    if (e < N_EDGES) {
        atomicAdd(&cnt1[edst[e]], 1);
        atomicAdd(&cnt2[esrc[e]], 1);
    }
}

// Two blocks: block b scans off + b*N_NODES (in place, exclusive).
__global__ void exscan_both(int* __restrict__ offbase) {
    int* a = offbase + (size_t)blockIdx.x * N_NODES;
    __shared__ int part[1024];
    int t = threadIdx.x;
    const int n = N_NODES;
    int chunk = (n + 1023) / 1024;
    int lo = t * chunk;
    int hi = min(lo + chunk, n);
    int s = 0;
    for (int i = lo; i < hi; ++i) s += a[i];
    part[t] = s;
    __syncthreads();
    for (int d = 1; d < 1024; d <<= 1) {
        int v = (t >= d) ? part[t - d] : 0;
        __syncthreads();
        part[t] += v;
        __syncthreads();
    }
    int base = (t == 0) ? 0 : part[t - 1];
    for (int i = lo; i < hi; ++i) { int v = a[i]; a[i] = base; base += v; }
}

// CSR-ordered payload: csr[p] = {neighbor, weight_bits}. After this kernel
// off[n] = end(n); start(n) = (n==0) ? 0 : off[n-1].
__global__ void scatter_both(const int* __restrict__ esrc, const int* __restrict__ edst,
                             const float* __restrict__ ew,
                             int* __restrict__ off1, int2* __restrict__ csr1,
                             int* __restrict__ off2, int2* __restrict__ csr2) {
    int e = blockIdx.x * blockDim.x + threadIdx.x;
    if (e < N_EDGES) {
        int s = esrc[e], d = edst[e];
        int wbits = __float_as_int(ew[e]);
        int p1 = atomicAdd(&off1[d], 1);
        csr1[p1] = make_int2(s, wbits);
        int p2 = atomicAdd(&off2[s], 1);
        csr2[p2] = make_int2(d, wbits);
    }
}

// ---------------------------------------------------------------------------
// Fused gather-aggregate, both directions. One wave per (node, dir); lane
// handles 2 features. 2-way unrolled so two feature-row loads are in flight.
// Reads bf16 feat from Ah[:,256:384]; writes mean into Ah[:,0:128]/[:,128:256].
// ---------------------------------------------------------------------------
__global__ void gather_both(u16* __restrict__ Ah,
                            const int* __restrict__ off1, const int2* __restrict__ csr1,
                            const int* __restrict__ off2, const int2* __restrict__ csr2) {
    int gw = (blockIdx.x * blockDim.x + threadIdx.x) >> 6;
    int lane = threadIdx.x & 63;
    if (gw >= 2 * N_NODES) return;
    int dir = (gw >= N_NODES);
    int n = dir ? gw - N_NODES : gw;
    const int*  off = dir ? off2 : off1;
    const int2* csr = dir ? csr2 : csr1;
    int start = (n == 0) ? 0 : off[n - 1];
    int end = off[n];
    float ax = 0.f, ay = 0.f, sw = 0.f;
    int p = start;
    for (; p + 1 < end; p += 2) {
        int2 e0 = csr[p];
        int2 e1 = csr[p + 1];
        u32 v0 = *(const u32*)(Ah + (size_t)e0.x * KTOT + 256 + lane * 2);
        u32 v1 = *(const u32*)(Ah + (size_t)e1.x * KTOT + 256 + lane * 2);
        float w0 = __int_as_float(e0.y), w1 = __int_as_float(e1.y);
        ax += b2f((u16)v0) * w0 + b2f((u16)v1) * w1;
        ay += b2f((u16)(v0 >> 16)) * w0 + b2f((u16)(v1 >> 16)) * w1;
        sw += w0 + w1;
    }
    if (p < end) {
        int2 e0 = csr[p];
        u32 v0 = *(const u32*)(Ah + (size_t)e0.x * KTOT + 256 + lane * 2);
        float w0 = __int_as_float(e0.y);
        ax += b2f((u16)v0) * w0;
        ay += b2f((u16)(v0 >> 16)) * w0;
        sw += w0;
    }
    float inv = (sw > 0.f) ? 1.f / sw : 0.f;
    if (!isfinite(inv)) inv = 0.f;
    u32 o = ((u32)f2b(ay * inv) << 16) | (u32)f2b(ax * inv);
    *(u32*)(Ah + (size_t)n * KTOT + dir * 128 + lane * 2) = o;
}

// ---------------------------------------------------------------------------
// Weight folding: M1 = W_ih[:, :128] @ W1 ; M2 = W_ih[:, 128:] @ W2 (fp32).
// ---------------------------------------------------------------------------
__global__ void compute_M(const float* __restrict__ W_ih,
                          const float* __restrict__ W1,
                          const float* __restrict__ W2,
                          float* __restrict__ M1, float* __restrict__ M2) {
    int r = blockIdx.x;          // 0..383
    int k = threadIdx.x;         // 0..127
    int which = blockIdx.y;
    const float* Wsel = which ? W2 : W1;
    const float* ih = W_ih + (size_t)r * (2 * D) + which * D;
    float acc = 0.f;
    for (int j = 0; j < D; ++j) acc += ih[j] * Wsel[j * D + k];
    (which ? M2 : M1)[r * D + k] = acc;
}

// ---------------------------------------------------------------------------
// Bt [512 cols][384 k] bf16, k-contiguous rows. Col c' = 4c+g:
//   g=0: r-sum rows c (M1|M2|W_hh); g=1: z-sum rows c+128;
//   g=2: gi_n rows c+256 (M1|M2|0); g=3: gh_n (0|0|W_hh row c+256)
// ---------------------------------------------------------------------------
__global__ void fill_Bt(const float* __restrict__ M1, const float* __restrict__ M2,
                        const float* __restrict__ W_hh, u16* __restrict__ Bt) {
    int idx = blockIdx.x * blockDim.x + threadIdx.x;
    if (idx >= NCOLS * KTOT) return;
    int cp = idx / KTOT;
    int k  = idx - cp * KTOT;
    int c = cp >> 2, g = cp & 3;
    float v = 0.f;
    if (g <= 1) {
        int r = c + (g == 1 ? 128 : 0);
        v = (k < 128) ? M1[r * D + k]
          : (k < 256) ? M2[r * D + (k - 128)]
                      : W_hh[r * D + (k - 256)];
    } else if (g == 2) {
        int r = c + 256;
        v = (k < 128) ? M1[r * D + k]
          : (k < 256) ? M2[r * D + (k - 128)] : 0.f;
    } else {
        v = (k >= 256) ? W_hh[(c + 256) * D + (k - 256)] : 0.f;
    }
    if (!isfinite(v)) v = 0.f;
    Bt[idx] = f2b(v);
}

// ---------------------------------------------------------------------------
// MFMA GEMM + fused GRU. Block 128x128 (2x2 waves of 64x64), K=384.
// Register double-buffered k-loop (fully unrolled, 12 steps): prefetch the
// next 8 fragments (b128 each) while the current 16 MFMAs execute.
// mfma_f32_16x16x32_bf16: A lane row=l&15, k=(l>>4)*8+j; C/D col=l&15,
// row=(l>>4)*4+reg [m89]. Gate de-interleave via per-wave LDS transpose.
// ---------------------------------------------------------------------------
__global__ __launch_bounds__(256)
void gemm_gru_mfma(const u16* __restrict__ Ah, const u16* __restrict__ Bt,
                   const float* __restrict__ feat,
                   const float* __restrict__ b_ih, const float* __restrict__ b_hh,
                   float* __restrict__ out) {
    __shared__ float epi[4][16][65];
    int tid = threadIdx.x, lane = tid & 63, wid = tid >> 6;
    int wm = wid >> 1, wn = wid & 1;
    int mw = blockIdx.y * 128 + wm * 64;    // wave row (node) base
    int nw = blockIdx.x * 128 + wn * 64;    // wave gate-col base
    int rif = lane & 15, kg = lane >> 4;

    f32x4 acc[4][4];
    #pragma unroll
    for (int i = 0; i < 4; ++i)
        #pragma unroll
        for (int j = 0; j < 4; ++j)
            acc[i][j] = (f32x4){0.f, 0.f, 0.f, 0.f};

    const u16* aPtr[4];
    const u16* bPtr[4];
    #pragma unroll
    for (int mf = 0; mf < 4; ++mf) {
        int arow = min(mw + mf * 16 + rif, N_NODES - 1);
        aPtr[mf] = Ah + (size_t)arow * KTOT + kg * 8;
    }
    #pragma unroll
    for (int nf = 0; nf < 4; ++nf)
        bPtr[nf] = Bt + (size_t)(nw + nf * 16 + rif) * KTOT + kg * 8;

    bf16x8 ca[4], cb[4];
    #pragma unroll
    for (int mf = 0; mf < 4; ++mf) ca[mf] = *(const bf16x8*)(aPtr[mf]);
    #pragma unroll
    for (int nf = 0; nf < 4; ++nf) cb[nf] = *(const bf16x8*)(bPtr[nf]);

    #pragma unroll
    for (int ks = 0; ks < KTOT / 32; ++ks) {
        bf16x8 na[4], nb[4];
        if (ks < KTOT / 32 - 1) {
            #pragma unroll
            for (int mf = 0; mf < 4; ++mf)
                na[mf] = *(const bf16x8*)(aPtr[mf] + (ks + 1) * 32);
            #pragma unroll
            for (int nf = 0; nf < 4; ++nf)
                nb[nf] = *(const bf16x8*)(bPtr[nf] + (ks + 1) * 32);
        }
        #pragma unroll
        for (int mf = 0; mf < 4; ++mf)
            #pragma unroll
            for (int nf = 0; nf < 4; ++nf)
                acc[mf][nf] = __builtin_amdgcn_mfma_f32_16x16x32_bf16(
                    ca[mf], cb[nf], acc[mf][nf], 0, 0, 0);
        if (ks < KTOT / 32 - 1) {
            #pragma unroll
            for (int mf = 0; mf < 4; ++mf) ca[mf] = na[mf];
            #pragma unroll
            for (int nf = 0; nf < 4; ++nf) cb[nf] = nb[nf];
        }
    }

    // ---- epilogue: de-interleave gates + GRU ----
    int rc0 = nw >> 2;          // wave real-col base (16 real cols)
    int erow = lane >> 2;       // 0..15
    int g4 = lane & 3;          // 4 real cols per lane
    int cbase = rc0 + g4 * 4;
    float4 bi_r = *(const float4*)(b_ih + cbase);
    float4 bh_r = *(const float4*)(b_hh + cbase);
    float4 bi_z = *(const float4*)(b_ih + cbase + 128);
    float4 bh_z = *(const float4*)(b_hh + cbase + 128);
    float4 bi_n = *(const float4*)(b_ih + cbase + 256);
    float4 bh_n = *(const float4*)(b_hh + cbase + 256);

    #pragma unroll
    for (int mf = 0; mf < 4; ++mf) {
        __syncthreads();
        #pragma unroll
        for (int nf = 0; nf < 4; ++nf)
            #pragma unroll
            for (int reg = 0; reg < 4; ++reg)
                epi[wid][kg * 4 + reg][nf * 16 + rif] = acc[mf][nf][reg];
        __syncthreads();

        float4 q0 = *(const float4*)&epi[wid][erow][g4 * 16 + 0];
        float4 q1 = *(const float4*)&epi[wid][erow][g4 * 16 + 4];
        float4 q2 = *(const float4*)&epi[wid][erow][g4 * 16 + 8];
        float4 q3 = *(const float4*)&epi[wid][erow][g4 * 16 + 12];

        int node = mw + mf * 16 + erow;
        if (node < N_NODES) {
            float4 f = *(const float4*)(feat + (size_t)node * D + cbase);
            float4 res;
            {
                float r = 1.f / (1.f + __expf(-(q0.x + bi_r.x + bh_r.x)));
                float z = 1.f / (1.f + __expf(-(q0.y + bi_z.x + bh_z.x)));
                float ng = tanhf(q0.z + bi_n.x + r * (q0.w + bh_n.x));
                res.x = (1.f - z) * ng + z * f.x;
            }
            {
                float r = 1.f / (1.f + __expf(-(q1.x + bi_r.y + bh_r.y)));
                float z = 1.f / (1.f + __expf(-(q1.y + bi_z.y + bh_z.y)));
                float ng = tanhf(q1.z + bi_n.y + r * (q1.w + bh_n.y));
                res.y = (1.f - z) * ng + z * f.y;
            }
            {
                float r = 1.f / (1.f + __expf(-(q2.x + bi_r.z + bh_r.z)));
                float z = 1.f / (1.f + __expf(-(q2.y + bi_z.z + bh_z.z)));
                float ng = tanhf(q2.z + bi_n.z + r * (q2.w + bh_n.z));
                res.z = (1.f - z) * ng + z * f.z;
            }
            {
                float r = 1.f / (1.f + __expf(-(q3.x + bi_r.w + bh_r.w)));
                float z = 1.f / (1.f + __expf(-(q3.y + bi_z.w + bh_z.w)));
                float ng = tanhf(q3.z + bi_n.w + r * (q3.w + bh_n.w));
                res.w = (1.f - z) * ng + z * f.w;
            }
            *(float4*)(out + (size_t)node * D + cbase) = res;
        }
    }
}

// ===========================================================================
extern "C" void kernel_launch(void* const* d_in, const int* in_sizes, int n_in,
                              void* d_out, int out_size, void* d_ws, size_t ws_size,
                              hipStream_t stream) {
    const float* feat = (const float*)d_in[0];
    const int*   esrc = (const int*)d_in[1];
    const int*   edst = (const int*)d_in[2];
    const float* ew   = (const float*)d_in[3];
    const float* W1   = (const float*)d_in[4];
    const float* W2   = (const float*)d_in[5];
    const float* W_ih = (const float*)d_in[6];
    const float* W_hh = (const float*)d_in[7];
    const float* b_ih = (const float*)d_in[8];
    const float* b_hh = (const float*)d_in[9];
    float* out = (float*)d_out;

    // ws words: Ah 9.6M | off1 50K | off2 50K | csr1 1.2M | csr2 1.2M
    //         | M1 49152 | M2 49152 | Bt 98304   (~49.2 MB)
    const size_t AH_ELEMS = (size_t)N_NODES * KTOT;  // u16 count
    const size_t needWords = AH_ELEMS / 2 + 2 * N_NODES + 4 * (size_t)N_EDGES
                           + 2 * (size_t)KTOT * D + (NCOLS * KTOT) / 2;
    if (ws_size < needWords * 4) {
        fill_sentinel<<<512, 256, 0, stream>>>(out, (long)out_size, 12345.0f);
        return;
    }

    u16*   Ah   = (u16*)d_ws;
    int*   off1 = (int*)(Ah + AH_ELEMS);
    int*   off2 = off1 + N_NODES;
    int2*  csr1 = (int2*)(off2 + N_NODES);
    int2*  csr2 = csr1 + N_EDGES;
    float* M1   = (float*)(csr2 + N_EDGES);
    float* M2   = M1 + KTOT * D;
    u16*   Bt   = (u16*)(M2 + KTOT * D);

    const int EB = (N_EDGES + 255) / 256;

    convert_feat<<<(N_NODES * (D / 4) + 255) / 256, 256, 0, stream>>>(feat, Ah);

    zero_words<<<(2 * N_NODES + 255) / 256, 256, 0, stream>>>((u32*)off1, 2 * N_NODES);
    count_both<<<EB, 256, 0, stream>>>(esrc, edst, off1, off2);
    exscan_both<<<2, 1024, 0, stream>>>(off1);
    scatter_both<<<EB, 256, 0, stream>>>(esrc, edst, ew, off1, csr1, off2, csr2);
    gather_both<<<(2 * N_NODES * 64 + 255) / 256, 256, 0, stream>>>(
        Ah, off1, csr1, off2, csr2);

    compute_M<<<dim3(KTOT, 2), 128, 0, stream>>>(W_ih, W1, W2, M1, M2);
    fill_Bt<<<(NCOLS * KTOT + 255) / 256, 256, 0, stream>>>(M1, M2, W_hh, Bt);

    gemm_gru_mfma<<<dim3(NCOLS / 128, (N_NODES + 127) / 128), 256, 0, stream>>>(
        Ah, Bt, feat, b_ih, b_hh, out);
}

// Round 8
// 353.273 us; speedup vs baseline: 3.8420x; 1.1248x over previous
//
#include <hip/hip_runtime.h>
#include <math.h>

#define N_NODES 50000
#define N_EDGES 600000
#define D 128
#define KTOT 384    // 3*D  (k: [n1 | n2 | feat])
#define NCOLS 512   // 4*D  (gate-interleaved cols: c' = 4c+g)

#define SCAN_CHUNK 512
#define SCAN_NB ((N_NODES + SCAN_CHUNK - 1) / SCAN_CHUNK)   // 98

typedef unsigned int u32;
typedef unsigned short u16;

typedef __attribute__((ext_vector_type(8))) short bf16x8;   // 8 bf16 (4 VGPRs)
typedef __attribute__((ext_vector_type(4))) float f32x4;

__device__ __forceinline__ float b2f(u16 x) {
    u32 u = ((u32)x) << 16;
    float f; __builtin_memcpy(&f, &u, 4);
    return f;
}
__device__ __forceinline__ u16 f2b(float f) {   // RNE bf16
    u32 u; __builtin_memcpy(&u, &f, 4);
    u32 r = (u + 0x7fffu + ((u >> 16) & 1u)) >> 16;
    return (u16)r;
}

// ---------------------------------------------------------------------------
__global__ void zero_words(u32* __restrict__ p, long n) {
    long i = (long)blockIdx.x * blockDim.x + threadIdx.x;
    long stride = (long)gridDim.x * blockDim.x;
    for (; i < n; i += stride) p[i] = 0u;
}

__global__ void fill_sentinel(float* __restrict__ p, long n, float v) {
    long i = (long)blockIdx.x * blockDim.x + threadIdx.x;
    long stride = (long)gridDim.x * blockDim.x;
    for (; i < n; i += stride) p[i] = v;
}

// ---------------------------------------------------------------------------
// feat fp32 -> bf16 into Ah[:, 256:384]
// ---------------------------------------------------------------------------
__global__ void convert_feat(const float* __restrict__ feat, u16* __restrict__ Ah) {
    int i = blockIdx.x * blockDim.x + threadIdx.x;   // over N*D/4
    if (i >= N_NODES * (D / 4)) return;
    int n = i >> 5, j4 = i & 31;
    float4 v = *(const float4*)(feat + (size_t)n * D + j4 * 4);
    ushort4 o;
    o.x = f2b(v.x); o.y = f2b(v.y); o.z = f2b(v.z); o.w = f2b(v.w);
    *(ushort4*)(Ah + (size_t)n * KTOT + 256 + j4 * 4) = o;
}

// ---------------------------------------------------------------------------
// CSR build (both directions): count -> parallel 3-phase scan -> scatter.
// ---------------------------------------------------------------------------
__global__ void count_both(const int* __restrict__ esrc, const int* __restrict__ edst,
                           int* __restrict__ cnt1, int* __restrict__ cnt2) {
    int e = blockIdx.x * blockDim.x + threadIdx.x;
    if (e < N_EDGES) {
        atomicAdd(&cnt1[edst[e]], 1);
        atomicAdd(&cnt2[esrc[e]], 1);
    }
}

// Phase 1: per-block chunk sums. grid (SCAN_NB, 2), 256 threads, 2 elems/thread.
__global__ void scan_partial(const int* __restrict__ off, int* __restrict__ bsum) {
    int dir = blockIdx.y, bx = blockIdx.x, t = threadIdx.x;
    const int* a = off + (size_t)dir * N_NODES;
    int i0 = bx * SCAN_CHUNK + 2 * t;
    int s = 0;
    if (i0 < N_NODES) s += a[i0];
    if (i0 + 1 < N_NODES) s += a[i0 + 1];
    __shared__ int red[256];
    red[t] = s;
    __syncthreads();
    for (int d = 128; d > 0; d >>= 1) {
        if (t < d) red[t] += red[t + d];
        __syncthreads();
    }
    if (t == 0) bsum[dir * SCAN_NB + bx] = red[0];
}

// Phase 2: exclusive scan of the two bsum segments (one block, two halves).
__global__ void scan_bsums(int* __restrict__ bsum) {
    __shared__ int part[256];
    int t = threadIdx.x;
    int i = t & 127, dir = t >> 7;
    int v = (i < SCAN_NB) ? bsum[dir * SCAN_NB + i] : 0;
    part[t] = v;
    __syncthreads();
    for (int d = 1; d < 128; d <<= 1) {
        int add = (i >= d) ? part[t - d] : 0;
        __syncthreads();
        part[t] += add;
        __syncthreads();
    }
    if (i < SCAN_NB) bsum[dir * SCAN_NB + i] = part[t] - v;  // exclusive
}

// Phase 3: in-place exclusive scan of each chunk + block base.
__global__ void scan_final(int* __restrict__ off, const int* __restrict__ bsum) {
    int dir = blockIdx.y, bx = blockIdx.x, t = threadIdx.x;
    int* a = off + (size_t)dir * N_NODES;
    int base = bsum[dir * SCAN_NB + bx];
    int i0 = bx * SCAN_CHUNK + 2 * t;
    int e0 = (i0 < N_NODES) ? a[i0] : 0;
    int e1 = (i0 + 1 < N_NODES) ? a[i0 + 1] : 0;
    __shared__ int part[256];
    int v = e0 + e1;
    part[t] = v;
    __syncthreads();
    for (int d = 1; d < 256; d <<= 1) {
        int add = (t >= d) ? part[t - d] : 0;
        __syncthreads();
        part[t] += add;
        __syncthreads();
    }
    int tb = base + part[t] - v;   // exclusive prefix for this thread
    if (i0 < N_NODES) a[i0] = tb;
    if (i0 + 1 < N_NODES) a[i0 + 1] = tb + e0;
}

// Packed CSR entry: (nbr << 16) | bf16(w).  N_NODES < 2^16, w >= 0.
// After this kernel off[n] = end(n); start(n) = (n==0) ? 0 : off[n-1].
__global__ void scatter_both(const int* __restrict__ esrc, const int* __restrict__ edst,
                             const float* __restrict__ ew,
                             int* __restrict__ off1, u32* __restrict__ csr1,
                             int* __restrict__ off2, u32* __restrict__ csr2) {
    int e = blockIdx.x * blockDim.x + threadIdx.x;
    if (e < N_EDGES) {
        int s = esrc[e], d = edst[e];
        u32 wb = (u32)f2b(ew[e]);
        int p1 = atomicAdd(&off1[d], 1);
        csr1[p1] = ((u32)s << 16) | wb;
        int p2 = atomicAdd(&off2[s], 1);
        csr2[p2] = ((u32)d << 16) | wb;
    }
}

// ---------------------------------------------------------------------------
// Fused gather-aggregate, both directions. One wave per (node, dir); lane
// handles 2 features; 2-way unrolled. Writes mean into Ah[:,0:128]/[:,128:256].
// ---------------------------------------------------------------------------
__global__ void gather_both(u16* __restrict__ Ah,
                            const int* __restrict__ off1, const u32* __restrict__ csr1,
                            const int* __restrict__ off2, const u32* __restrict__ csr2) {
    int gw = (blockIdx.x * blockDim.x + threadIdx.x) >> 6;
    int lane = threadIdx.x & 63;
    if (gw >= 2 * N_NODES) return;
    int dir = (gw >= N_NODES);
    int n = dir ? gw - N_NODES : gw;
    const int* off = dir ? off2 : off1;
    const u32* csr = dir ? csr2 : csr1;
    int start = (n == 0) ? 0 : off[n - 1];
    int end = off[n];
    float ax = 0.f, ay = 0.f, sw = 0.f;
    int p = start;
    for (; p + 1 < end; p += 2) {
        u32 c0 = csr[p];
        u32 c1 = csr[p + 1];
        u32 v0 = *(const u32*)(Ah + (size_t)(c0 >> 16) * KTOT + 256 + lane * 2);
        u32 v1 = *(const u32*)(Ah + (size_t)(c1 >> 16) * KTOT + 256 + lane * 2);
        float w0 = b2f((u16)c0), w1 = b2f((u16)c1);
        ax += b2f((u16)v0) * w0 + b2f((u16)v1) * w1;
        ay += b2f((u16)(v0 >> 16)) * w0 + b2f((u16)(v1 >> 16)) * w1;
        sw += w0 + w1;
    }
    if (p < end) {
        u32 c0 = csr[p];
        u32 v0 = *(const u32*)(Ah + (size_t)(c0 >> 16) * KTOT + 256 + lane * 2);
        float w0 = b2f((u16)c0);
        ax += b2f((u16)v0) * w0;
        ay += b2f((u16)(v0 >> 16)) * w0;
        sw += w0;
    }
    float inv = (sw > 0.f) ? 1.f / sw : 0.f;
    if (!isfinite(inv)) inv = 0.f;
    u32 o = ((u32)f2b(ay * inv) << 16) | (u32)f2b(ax * inv);
    *(u32*)(Ah + (size_t)n * KTOT + dir * 128 + lane * 2) = o;
}

// ---------------------------------------------------------------------------
// Weight folding: M1 = W_ih[:, :128] @ W1 ; M2 = W_ih[:, 128:] @ W2 (fp32).
// ---------------------------------------------------------------------------
__global__ void compute_M(const float* __restrict__ W_ih,
                          const float* __restrict__ W1,
                          const float* __restrict__ W2,
                          float* __restrict__ M1, float* __restrict__ M2) {
    int r = blockIdx.x;          // 0..383
    int k = threadIdx.x;         // 0..127
    int which = blockIdx.y;
    const float* Wsel = which ? W2 : W1;
    const float* ih = W_ih + (size_t)r * (2 * D) + which * D;
    float acc = 0.f;
    for (int j = 0; j < D; ++j) acc += ih[j] * Wsel[j * D + k];
    (which ? M2 : M1)[r * D + k] = acc;
}

// ---------------------------------------------------------------------------
// Bt [512 cols][384 k] bf16, k-contiguous rows. Col c' = 4c+g:
//   g=0: r-sum rows c (M1|M2|W_hh); g=1: z-sum rows c+128;
//   g=2: gi_n rows c+256 (M1|M2|0); g=3: gh_n (0|0|W_hh row c+256)
// ---------------------------------------------------------------------------
__global__ void fill_Bt(const float* __restrict__ M1, const float* __restrict__ M2,
                        const float* __restrict__ W_hh, u16* __restrict__ Bt) {
    int idx = blockIdx.x * blockDim.x + threadIdx.x;
    if (idx >= NCOLS * KTOT) return;
    int cp = idx / KTOT;
    int k  = idx - cp * KTOT;
    int c = cp >> 2, g = cp & 3;
    float v = 0.f;
    if (g <= 1) {
        int r = c + (g == 1 ? 128 : 0);
        v = (k < 128) ? M1[r * D + k]
          : (k < 256) ? M2[r * D + (k - 128)]
                      : W_hh[r * D + (k - 256)];
    } else if (g == 2) {
        int r = c + 256;
        v = (k < 128) ? M1[r * D + k]
          : (k < 256) ? M2[r * D + (k - 128)] : 0.f;
    } else {
        v = (k >= 256) ? W_hh[(c + 256) * D + (k - 256)] : 0.f;
    }
    if (!isfinite(v)) v = 0.f;
    Bt[idx] = f2b(v);
}

// ---------------------------------------------------------------------------
// MFMA GEMM + fused GRU. Wave tile 32x64 (acc 2x4 f32x4 = 32 AGPR), block =
// 4 waves stacked -> 128x64; grid (8, 391) = 3128 blocks (2x round-7 TLP).
// Depth-2 even/odd register pipeline: loads for step ks+2 issued before the
// MFMAs of step ks+1. mfma_f32_16x16x32_bf16: A lane row=l&15, k=(l>>4)*8+j;
// C/D col=l&15, row=(l>>4)*4+reg [m89]. Gate de-interleave via LDS transpose.
// ---------------------------------------------------------------------------
__global__ __launch_bounds__(256)
void gemm_gru_mfma(const u16* __restrict__ Ah, const u16* __restrict__ Bt,
                   const float* __restrict__ feat,
                   const float* __restrict__ b_ih, const float* __restrict__ b_hh,
                   float* __restrict__ out) {
    __shared__ float epi[4][16][65];
    int tid = threadIdx.x, lane = tid & 63, wid = tid >> 6;
    int mw = blockIdx.y * 128 + wid * 32;   // wave row (node) base
    int nw = blockIdx.x * 64;               // wave gate-col base
    int rif = lane & 15, kg = lane >> 4;

    f32x4 acc[2][4];
    #pragma unroll
    for (int m = 0; m < 2; ++m)
        #pragma unroll
        for (int n = 0; n < 4; ++n)
            acc[m][n] = (f32x4){0.f, 0.f, 0.f, 0.f};

    const u16* aP[2];
    const u16* bP[4];
    #pragma unroll
    for (int m = 0; m < 2; ++m) {
        int arow = min(mw + m * 16 + rif, N_NODES - 1);
        aP[m] = Ah + (size_t)arow * KTOT + kg * 8;
    }
    #pragma unroll
    for (int n = 0; n < 4; ++n)
        bP[n] = Bt + (size_t)(nw + n * 16 + rif) * KTOT + kg * 8;

    bf16x8 ea[2], eb[4], oa[2], ob[4];
    #pragma unroll
    for (int m = 0; m < 2; ++m) ea[m] = *(const bf16x8*)(aP[m]);
    #pragma unroll
    for (int n = 0; n < 4; ++n) eb[n] = *(const bf16x8*)(bP[n]);
    #pragma unroll
    for (int m = 0; m < 2; ++m) oa[m] = *(const bf16x8*)(aP[m] + 32);
    #pragma unroll
    for (int n = 0; n < 4; ++n) ob[n] = *(const bf16x8*)(bP[n] + 32);

    #pragma unroll
    for (int ks = 0; ks < KTOT / 32; ks += 2) {
        #pragma unroll
        for (int m = 0; m < 2; ++m)
            #pragma unroll
            for (int n = 0; n < 4; ++n)
                acc[m][n] = __builtin_amdgcn_mfma_f32_16x16x32_bf16(
                    ea[m], eb[n], acc[m][n], 0, 0, 0);
        if (ks + 2 < KTOT / 32) {
            #pragma unroll
            for (int m = 0; m < 2; ++m) ea[m] = *(const bf16x8*)(aP[m] + (ks + 2) * 32);
            #pragma unroll
            for (int n = 0; n < 4; ++n) eb[n] = *(const bf16x8*)(bP[n] + (ks + 2) * 32);
        }
        #pragma unroll
        for (int m = 0; m < 2; ++m)
            #pragma unroll
            for (int n = 0; n < 4; ++n)
                acc[m][n] = __builtin_amdgcn_mfma_f32_16x16x32_bf16(
                    oa[m], ob[n], acc[m][n], 0, 0, 0);
        if (ks + 3 < KTOT / 32) {
            #pragma unroll
            for (int m = 0; m < 2; ++m) oa[m] = *(const bf16x8*)(aP[m] + (ks + 3) * 32);
            #pragma unroll
            for (int n = 0; n < 4; ++n) ob[n] = *(const bf16x8*)(bP[n] + (ks + 3) * 32);
        }
    }

    // ---- epilogue: de-interleave gates + GRU ----
    int rc0 = nw >> 2;          // wave real-col base (16 real cols)
    int erow = lane >> 2;       // 0..15
    int g4 = lane & 3;          // 4 real cols per lane
    int cbase = rc0 + g4 * 4;
    float4 bi_r = *(const float4*)(b_ih + cbase);
    float4 bh_r = *(const float4*)(b_hh + cbase);
    float4 bi_z = *(const float4*)(b_ih + cbase + 128);
    float4 bh_z = *(const float4*)(b_hh + cbase + 128);
    float4 bi_n = *(const float4*)(b_ih + cbase + 256);
    float4 bh_n = *(const float4*)(b_hh + cbase + 256);

    #pragma unroll
    for (int m = 0; m < 2; ++m) {
        __syncthreads();
        #pragma unroll
        for (int n = 0; n < 4; ++n)
            #pragma unroll
            for (int reg = 0; reg < 4; ++reg)
                epi[wid][kg * 4 + reg][n * 16 + rif] = acc[m][n][reg];
        __syncthreads();

        float4 q0 = *(const float4*)&epi[wid][erow][g4 * 16 + 0];
        float4 q1 = *(const float4*)&epi[wid][erow][g4 * 16 + 4];
        float4 q2 = *(const float4*)&epi[wid][erow][g4 * 16 + 8];
        float4 q3 = *(const float4*)&epi[wid][erow][g4 * 16 + 12];

        int node = mw + m * 16 + erow;
        if (node < N_NODES) {
            float4 f = *(const float4*)(feat + (size_t)node * D + cbase);
            float4 res;
            {
                float r = 1.f / (1.f + __expf(-(q0.x + bi_r.x + bh_r.x)));
                float z = 1.f / (1.f + __expf(-(q0.y + bi_z.x + bh_z.x)));
                float ng = tanhf(q0.z + bi_n.x + r * (q0.w + bh_n.x));
                res.x = (1.f - z) * ng + z * f.x;
            }
            {
                float r = 1.f / (1.f + __expf(-(q1.x + bi_r.y + bh_r.y)));
                float z = 1.f / (1.f + __expf(-(q1.y + bi_z.y + bh_z.y)));
                float ng = tanhf(q1.z + bi_n.y + r * (q1.w + bh_n.y));
                res.y = (1.f - z) * ng + z * f.y;
            }
            {
                float r = 1.f / (1.f + __expf(-(q2.x + bi_r.z + bh_r.z)));
                float z = 1.f / (1.f + __expf(-(q2.y + bi_z.z + bh_z.z)));
                float ng = tanhf(q2.z + bi_n.z + r * (q2.w + bh_n.z));
                res.z = (1.f - z) * ng + z * f.z;
            }
            {
                float r = 1.f / (1.f + __expf(-(q3.x + bi_r.w + bh_r.w)));
                float z = 1.f / (1.f + __expf(-(q3.y + bi_z.w + bh_z.w)));
                float ng = tanhf(q3.z + bi_n.w + r * (q3.w + bh_n.w));
                res.w = (1.f - z) * ng + z * f.w;
            }
            *(float4*)(out + (size_t)node * D + cbase) = res;
        }
    }
}

// ===========================================================================
extern "C" void kernel_launch(void* const* d_in, const int* in_sizes, int n_in,
                              void* d_out, int out_size, void* d_ws, size_t ws_size,
                              hipStream_t stream) {
    const float* feat = (const float*)d_in[0];
    const int*   esrc = (const int*)d_in[1];
    const int*   edst = (const int*)d_in[2];
    const float* ew   = (const float*)d_in[3];
    const float* W1   = (const float*)d_in[4];
    const float* W2   = (const float*)d_in[5];
    const float* W_ih = (const float*)d_in[6];
    const float* W_hh = (const float*)d_in[7];
    const float* b_ih = (const float*)d_in[8];
    const float* b_hh = (const float*)d_in[9];
    float* out = (float*)d_out;

    // ws words: Ah 9.6M | off 100K | csr1 600K | csr2 600K | bsum 256
    //         | M1 49152 | M2 49152 | Bt 98304  (~44.4 MB)
    const size_t AH_ELEMS = (size_t)N_NODES * KTOT;  // u16 count
    const size_t needWords = AH_ELEMS / 2 + 2 * N_NODES + 2 * (size_t)N_EDGES
                           + 256 + 2 * (size_t)KTOT * D + (NCOLS * KTOT) / 2;
    if (ws_size < needWords * 4) {
        fill_sentinel<<<512, 256, 0, stream>>>(out, (long)out_size, 12345.0f);
        return;
    }

    u16*   Ah   = (u16*)d_ws;
    int*   off1 = (int*)(Ah + AH_ELEMS);
    int*   off2 = off1 + N_NODES;
    u32*   csr1 = (u32*)(off2 + N_NODES);
    u32*   csr2 = csr1 + N_EDGES;
    int*   bsum = (int*)(csr2 + N_EDGES);
    float* M1   = (float*)(bsum + 256);
    float* M2   = M1 + KTOT * D;
    u16*   Bt   = (u16*)(M2 + KTOT * D);

    const int EB = (N_EDGES + 255) / 256;

    convert_feat<<<(N_NODES * (D / 4) + 255) / 256, 256, 0, stream>>>(feat, Ah);

    zero_words<<<(2 * N_NODES + 255) / 256, 256, 0, stream>>>((u32*)off1, 2 * N_NODES);
    count_both<<<EB, 256, 0, stream>>>(esrc, edst, off1, off2);
    scan_partial<<<dim3(SCAN_NB, 2), 256, 0, stream>>>(off1, bsum);
    scan_bsums<<<1, 256, 0, stream>>>(bsum);
    scan_final<<<dim3(SCAN_NB, 2), 256, 0, stream>>>(off1, bsum);
    scatter_both<<<EB, 256, 0, stream>>>(esrc, edst, ew, off1, csr1, off2, csr2);
    gather_both<<<(2 * N_NODES * 64 + 255) / 256, 256, 0, stream>>>(
        Ah, off1, csr1, off2, csr2);

    compute_M<<<dim3(KTOT, 2), 128, 0, stream>>>(W_ih, W1, W2, M1, M2);
    fill_Bt<<<(NCOLS * KTOT + 255) / 256, 256, 0, stream>>>(M1, M2, W_hh, Bt);

    gemm_gru_mfma<<<dim3(NCOLS / 64, (N_NODES + 127) / 128), 256, 0, stream>>>(
        Ah, Bt, feat, b_ih, b_hh, out);
}

// Round 9
// 335.940 us; speedup vs baseline: 4.0402x; 1.0516x over previous
//
#include <hip/hip_runtime.h>
#include <math.h>

#define N_NODES 50000
#define N_EDGES 600000
#define D 128
#define KTOT 384    // 3*D  (k: [n1 | n2 | feat])
#define NCOLS 512   // 4*D  (gate-interleaved cols: c' = 4c+g)

#define SCAN_CHUNK 512
#define SCAN_NB ((N_NODES + SCAN_CHUNK - 1) / SCAN_CHUNK)   // 98

#define GEMM_ROWB ((N_NODES + 127) / 128)    // 391 row panels
#define GEMM_NWG  (GEMM_ROWB * 8)            // 3128 blocks, 8 col-blocks
#define NXCD 8

typedef unsigned int u32;
typedef unsigned short u16;

typedef __attribute__((ext_vector_type(8))) short bf16x8;   // 8 bf16 (4 VGPRs)
typedef __attribute__((ext_vector_type(4))) float f32x4;

__device__ __forceinline__ float b2f(u16 x) {
    u32 u = ((u32)x) << 16;
    float f; __builtin_memcpy(&f, &u, 4);
    return f;
}
__device__ __forceinline__ u16 f2b(float f) {   // RNE bf16
    u32 u; __builtin_memcpy(&u, &f, 4);
    u32 r = (u + 0x7fffu + ((u >> 16) & 1u)) >> 16;
    return (u16)r;
}

// ---------------------------------------------------------------------------
__global__ void zero_words(u32* __restrict__ p, long n) {
    long i = (long)blockIdx.x * blockDim.x + threadIdx.x;
    long stride = (long)gridDim.x * blockDim.x;
    for (; i < n; i += stride) p[i] = 0u;
}

__global__ void fill_sentinel(float* __restrict__ p, long n, float v) {
    long i = (long)blockIdx.x * blockDim.x + threadIdx.x;
    long stride = (long)gridDim.x * blockDim.x;
    for (; i < n; i += stride) p[i] = v;
}

// ---------------------------------------------------------------------------
// feat fp32 -> bf16 into Ah[:, 256:384]
// ---------------------------------------------------------------------------
__global__ void convert_feat(const float* __restrict__ feat, u16* __restrict__ Ah) {
    int i = blockIdx.x * blockDim.x + threadIdx.x;   // over N*D/4
    if (i >= N_NODES * (D / 4)) return;
    int n = i >> 5, j4 = i & 31;
    float4 v = *(const float4*)(feat + (size_t)n * D + j4 * 4);
    ushort4 o;
    o.x = f2b(v.x); o.y = f2b(v.y); o.z = f2b(v.z); o.w = f2b(v.w);
    *(ushort4*)(Ah + (size_t)n * KTOT + 256 + j4 * 4) = o;
}

// ---------------------------------------------------------------------------
// CSR build (both directions): count -> parallel 3-phase scan -> scatter.
// ---------------------------------------------------------------------------
__global__ void count_both(const int* __restrict__ esrc, const int* __restrict__ edst,
                           int* __restrict__ cnt1, int* __restrict__ cnt2) {
    int e = blockIdx.x * blockDim.x + threadIdx.x;
    if (e < N_EDGES) {
        atomicAdd(&cnt1[edst[e]], 1);
        atomicAdd(&cnt2[esrc[e]], 1);
    }
}

// Phase 1: per-block chunk sums. grid (SCAN_NB, 2), 256 threads, 2 elems/thread.
__global__ void scan_partial(const int* __restrict__ off, int* __restrict__ bsum) {
    int dir = blockIdx.y, bx = blockIdx.x, t = threadIdx.x;
    const int* a = off + (size_t)dir * N_NODES;
    int i0 = bx * SCAN_CHUNK + 2 * t;
    int s = 0;
    if (i0 < N_NODES) s += a[i0];
    if (i0 + 1 < N_NODES) s += a[i0 + 1];
    __shared__ int red[256];
    red[t] = s;
    __syncthreads();
    for (int d = 128; d > 0; d >>= 1) {
        if (t < d) red[t] += red[t + d];
        __syncthreads();
    }
    if (t == 0) bsum[dir * SCAN_NB + bx] = red[0];
}

// Phase 2: exclusive scan of the two bsum segments (one block, two halves).
__global__ void scan_bsums(int* __restrict__ bsum) {
    __shared__ int part[256];
    int t = threadIdx.x;
    int i = t & 127, dir = t >> 7;
    int v = (i < SCAN_NB) ? bsum[dir * SCAN_NB + i] : 0;
    part[t] = v;
    __syncthreads();
    for (int d = 1; d < 128; d <<= 1) {
        int add = (i >= d) ? part[t - d] : 0;
        __syncthreads();
        part[t] += add;
        __syncthreads();
    }
    if (i < SCAN_NB) bsum[dir * SCAN_NB + i] = part[t] - v;  // exclusive
}

// Phase 3: in-place exclusive scan of each chunk + block base.
__global__ void scan_final(int* __restrict__ off, const int* __restrict__ bsum) {
    int dir = blockIdx.y, bx = blockIdx.x, t = threadIdx.x;
    int* a = off + (size_t)dir * N_NODES;
    int base = bsum[dir * SCAN_NB + bx];
    int i0 = bx * SCAN_CHUNK + 2 * t;
    int e0 = (i0 < N_NODES) ? a[i0] : 0;
    int e1 = (i0 + 1 < N_NODES) ? a[i0 + 1] : 0;
    __shared__ int part[256];
    int v = e0 + e1;
    part[t] = v;
    __syncthreads();
    for (int d = 1; d < 256; d <<= 1) {
        int add = (t >= d) ? part[t - d] : 0;
        __syncthreads();
        part[t] += add;
        __syncthreads();
    }
    int tb = base + part[t] - v;   // exclusive prefix for this thread
    if (i0 < N_NODES) a[i0] = tb;
    if (i0 + 1 < N_NODES) a[i0 + 1] = tb + e0;
}

// Packed CSR entry: (nbr << 16) | bf16(w).  N_NODES < 2^16, w >= 0.
// After this kernel off[n] = end(n); start(n) = (n==0) ? 0 : off[n-1].
__global__ void scatter_both(const int* __restrict__ esrc, const int* __restrict__ edst,
                             const float* __restrict__ ew,
                             int* __restrict__ off1, u32* __restrict__ csr1,
                             int* __restrict__ off2, u32* __restrict__ csr2) {
    int e = blockIdx.x * blockDim.x + threadIdx.x;
    if (e < N_EDGES) {
        int s = esrc[e], d = edst[e];
        u32 wb = (u32)f2b(ew[e]);
        int p1 = atomicAdd(&off1[d], 1);
        csr1[p1] = ((u32)s << 16) | wb;
        int p2 = atomicAdd(&off2[s], 1);
        csr2[p2] = ((u32)d << 16) | wb;
    }
}

// ---------------------------------------------------------------------------
// Fused gather-aggregate, both directions. One wave per (node, dir); lane
// handles 2 features; 4-way unrolled (4 feature-row loads in flight).
// Writes mean into Ah[:,0:128]/[:,128:256].
// ---------------------------------------------------------------------------
__global__ void gather_both(u16* __restrict__ Ah,
                            const int* __restrict__ off1, const u32* __restrict__ csr1,
                            const int* __restrict__ off2, const u32* __restrict__ csr2) {
    int gw = (blockIdx.x * blockDim.x + threadIdx.x) >> 6;
    int lane = threadIdx.x & 63;
    if (gw >= 2 * N_NODES) return;
    int dir = (gw >= N_NODES);
    int n = dir ? gw - N_NODES : gw;
    const int* off = dir ? off2 : off1;
    const u32* csr = dir ? csr2 : csr1;
    int start = (n == 0) ? 0 : off[n - 1];
    int end = off[n];
    float ax = 0.f, ay = 0.f, sw = 0.f;
    int p = start;
    for (; p + 3 < end; p += 4) {
        u32 c0 = csr[p], c1 = csr[p + 1], c2 = csr[p + 2], c3 = csr[p + 3];
        u32 v0 = *(const u32*)(Ah + (size_t)(c0 >> 16) * KTOT + 256 + lane * 2);
        u32 v1 = *(const u32*)(Ah + (size_t)(c1 >> 16) * KTOT + 256 + lane * 2);
        u32 v2 = *(const u32*)(Ah + (size_t)(c2 >> 16) * KTOT + 256 + lane * 2);
        u32 v3 = *(const u32*)(Ah + (size_t)(c3 >> 16) * KTOT + 256 + lane * 2);
        float w0 = b2f((u16)c0), w1 = b2f((u16)c1);
        float w2 = b2f((u16)c2), w3 = b2f((u16)c3);
        ax += b2f((u16)v0) * w0 + b2f((u16)v1) * w1
            + b2f((u16)v2) * w2 + b2f((u16)v3) * w3;
        ay += b2f((u16)(v0 >> 16)) * w0 + b2f((u16)(v1 >> 16)) * w1
            + b2f((u16)(v2 >> 16)) * w2 + b2f((u16)(v3 >> 16)) * w3;
        sw += w0 + w1 + w2 + w3;
    }
    for (; p < end; ++p) {
        u32 c0 = csr[p];
        u32 v0 = *(const u32*)(Ah + (size_t)(c0 >> 16) * KTOT + 256 + lane * 2);
        float w0 = b2f((u16)c0);
        ax += b2f((u16)v0) * w0;
        ay += b2f((u16)(v0 >> 16)) * w0;
        sw += w0;
    }
    float inv = (sw > 0.f) ? 1.f / sw : 0.f;
    if (!isfinite(inv)) inv = 0.f;
    u32 o = ((u32)f2b(ay * inv) << 16) | (u32)f2b(ax * inv);
    *(u32*)(Ah + (size_t)n * KTOT + dir * 128 + lane * 2) = o;
}

// ---------------------------------------------------------------------------
// Weight folding: M1 = W_ih[:, :128] @ W1 ; M2 = W_ih[:, 128:] @ W2 (fp32).
// ---------------------------------------------------------------------------
__global__ void compute_M(const float* __restrict__ W_ih,
                          const float* __restrict__ W1,
                          const float* __restrict__ W2,
                          float* __restrict__ M1, float* __restrict__ M2) {
    int r = blockIdx.x;          // 0..383
    int k = threadIdx.x;         // 0..127
    int which = blockIdx.y;
    const float* Wsel = which ? W2 : W1;
    const float* ih = W_ih + (size_t)r * (2 * D) + which * D;
    float acc = 0.f;
    for (int j = 0; j < D; ++j) acc += ih[j] * Wsel[j * D + k];
    (which ? M2 : M1)[r * D + k] = acc;
}

// ---------------------------------------------------------------------------
// Bt [512 cols][384 k] bf16, k-contiguous rows. Col c' = 4c+g:
//   g=0: r-sum rows c (M1|M2|W_hh); g=1: z-sum rows c+128;
//   g=2: gi_n rows c+256 (M1|M2|0); g=3: gh_n (0|0|W_hh row c+256)
// ---------------------------------------------------------------------------
__global__ void fill_Bt(const float* __restrict__ M1, const float* __restrict__ M2,
                        const float* __restrict__ W_hh, u16* __restrict__ Bt) {
    int idx = blockIdx.x * blockDim.x + threadIdx.x;
    if (idx >= NCOLS * KTOT) return;
    int cp = idx / KTOT;
    int k  = idx - cp * KTOT;
    int c = cp >> 2, g = cp & 3;
    float v = 0.f;
    if (g <= 1) {
        int r = c + (g == 1 ? 128 : 0);
        v = (k < 128) ? M1[r * D + k]
          : (k < 256) ? M2[r * D + (k - 128)]
                      : W_hh[r * D + (k - 256)];
    } else if (g == 2) {
        int r = c + 256;
        v = (k < 128) ? M1[r * D + k]
          : (k < 256) ? M2[r * D + (k - 128)] : 0.f;
    } else {
        v = (k >= 256) ? W_hh[(c + 256) * D + (k - 256)] : 0.f;
    }
    if (!isfinite(v)) v = 0.f;
    Bt[idx] = f2b(v);
}

// ---------------------------------------------------------------------------
// MFMA GEMM + fused GRU. Wave tile 32x64, block 128x64, 1D grid of 3128 with
// XCD-aware bijective swizzle: wgid = (bid%8)*391 + bid/8; row = wgid/8,
// colb = wgid%8  ->  each XCD walks row-panels sequentially with all 8
// col-blocks adjacent, so the 98 KB A-panel is fetched from HBM once per XCD
// and re-read from L2 (T1 mechanism). Depth-2 even/odd register pipeline.
// mfma_f32_16x16x32_bf16: A lane row=l&15, k=(l>>4)*8+j; C/D col=l&15,
// row=(l>>4)*4+reg [m89]. Gate de-interleave via per-wave LDS transpose.
// ---------------------------------------------------------------------------
__global__ __launch_bounds__(256)
void gemm_gru_mfma(const u16* __restrict__ Ah, const u16* __restrict__ Bt,
                   const float* __restrict__ feat,
                   const float* __restrict__ b_ih, const float* __restrict__ b_hh,
                   float* __restrict__ out) {
    __shared__ float epi[4][16][65];
    int bid = blockIdx.x;
    int wgid = (bid % NXCD) * (GEMM_NWG / NXCD) + bid / NXCD;   // bijective
    int rowp = wgid >> 3;
    int colb = wgid & 7;
    int tid = threadIdx.x, lane = tid & 63, wid = tid >> 6;
    int mw = rowp * 128 + wid * 32;         // wave row (node) base
    int nw = colb * 64;                     // wave gate-col base
    int rif = lane & 15, kg = lane >> 4;

    f32x4 acc[2][4];
    #pragma unroll
    for (int m = 0; m < 2; ++m)
        #pragma unroll
        for (int n = 0; n < 4; ++n)
            acc[m][n] = (f32x4){0.f, 0.f, 0.f, 0.f};

    const u16* aP[2];
    const u16* bP[4];
    #pragma unroll
    for (int m = 0; m < 2; ++m) {
        int arow = min(mw + m * 16 + rif, N_NODES - 1);
        aP[m] = Ah + (size_t)arow * KTOT + kg * 8;
    }
    #pragma unroll
    for (int n = 0; n < 4; ++n)
        bP[n] = Bt + (size_t)(nw + n * 16 + rif) * KTOT + kg * 8;

    bf16x8 ea[2], eb[4], oa[2], ob[4];
    #pragma unroll
    for (int m = 0; m < 2; ++m) ea[m] = *(const bf16x8*)(aP[m]);
    #pragma unroll
    for (int n = 0; n < 4; ++n) eb[n] = *(const bf16x8*)(bP[n]);
    #pragma unroll
    for (int m = 0; m < 2; ++m) oa[m] = *(const bf16x8*)(aP[m] + 32);
    #pragma unroll
    for (int n = 0; n < 4; ++n) ob[n] = *(const bf16x8*)(bP[n] + 32);

    #pragma unroll
    for (int ks = 0; ks < KTOT / 32; ks += 2) {
        #pragma unroll
        for (int m = 0; m < 2; ++m)
            #pragma unroll
            for (int n = 0; n < 4; ++n)
                acc[m][n] = __builtin_amdgcn_mfma_f32_16x16x32_bf16(
                    ea[m], eb[n], acc[m][n], 0, 0, 0);
        if (ks + 2 < KTOT / 32) {
            #pragma unroll
            for (int m = 0; m < 2; ++m) ea[m] = *(const bf16x8*)(aP[m] + (ks + 2) * 32);
            #pragma unroll
            for (int n = 0; n < 4; ++n) eb[n] = *(const bf16x8*)(bP[n] + (ks + 2) * 32);
        }
        #pragma unroll
        for (int m = 0; m < 2; ++m)
            #pragma unroll
            for (int n = 0; n < 4; ++n)
                acc[m][n] = __builtin_amdgcn_mfma_f32_16x16x32_bf16(
                    oa[m], ob[n], acc[m][n], 0, 0, 0);
        if (ks + 3 < KTOT / 32) {
            #pragma unroll
            for (int m = 0; m < 2; ++m) oa[m] = *(const bf16x8*)(aP[m] + (ks + 3) * 32);
            #pragma unroll
            for (int n = 0; n < 4; ++n) ob[n] = *(const bf16x8*)(bP[n] + (ks + 3) * 32);
        }
    }

    // ---- epilogue: de-interleave gates + GRU ----
    int rc0 = nw >> 2;          // wave real-col base (16 real cols)
    int erow = lane >> 2;       // 0..15
    int g4 = lane & 3;          // 4 real cols per lane
    int cbase = rc0 + g4 * 4;
    float4 bi_r = *(const float4*)(b_ih + cbase);
    float4 bh_r = *(const float4*)(b_hh + cbase);
    float4 bi_z = *(const float4*)(b_ih + cbase + 128);
    float4 bh_z = *(const float4*)(b_hh + cbase + 128);
    float4 bi_n = *(const float4*)(b_ih + cbase + 256);
    float4 bh_n = *(const float4*)(b_hh + cbase + 256);

    #pragma unroll
    for (int m = 0; m < 2; ++m) {
        __syncthreads();
        #pragma unroll
        for (int n = 0; n < 4; ++n)
            #pragma unroll
            for (int reg = 0; reg < 4; ++reg)
                epi[wid][kg * 4 + reg][n * 16 + rif] = acc[m][n][reg];
        __syncthreads();

        float4 q0 = *(const float4*)&epi[wid][erow][g4 * 16 + 0];
        float4 q1 = *(const float4*)&epi[wid][erow][g4 * 16 + 4];
        float4 q2 = *(const float4*)&epi[wid][erow][g4 * 16 + 8];
        float4 q3 = *(const float4*)&epi[wid][erow][g4 * 16 + 12];

        int node = mw + m * 16 + erow;
        if (node < N_NODES) {
            float4 f = *(const float4*)(feat + (size_t)node * D + cbase);
            float4 res;
            {
                float r = 1.f / (1.f + __expf(-(q0.x + bi_r.x + bh_r.x)));
                float z = 1.f / (1.f + __expf(-(q0.y + bi_z.x + bh_z.x)));
                float ng = tanhf(q0.z + bi_n.x + r * (q0.w + bh_n.x));
                res.x = (1.f - z) * ng + z * f.x;
            }
            {
                float r = 1.f / (1.f + __expf(-(q1.x + bi_r.y + bh_r.y)));
                float z = 1.f / (1.f + __expf(-(q1.y + bi_z.y + bh_z.y)));
                float ng = tanhf(q1.z + bi_n.y + r * (q1.w + bh_n.y));
                res.y = (1.f - z) * ng + z * f.y;
            }
            {
                float r = 1.f / (1.f + __expf(-(q2.x + bi_r.z + bh_r.z)));
                float z = 1.f / (1.f + __expf(-(q2.y + bi_z.z + bh_z.z)));
                float ng = tanhf(q2.z + bi_n.z + r * (q2.w + bh_n.z));
                res.z = (1.f - z) * ng + z * f.z;
            }
            {
                float r = 1.f / (1.f + __expf(-(q3.x + bi_r.w + bh_r.w)));
                float z = 1.f / (1.f + __expf(-(q3.y + bi_z.w + bh_z.w)));
                float ng = tanhf(q3.z + bi_n.w + r * (q3.w + bh_n.w));
                res.w = (1.f - z) * ng + z * f.w;
            }
            *(float4*)(out + (size_t)node * D + cbase) = res;
        }
    }
}

// ===========================================================================
extern "C" void kernel_launch(void* const* d_in, const int* in_sizes, int n_in,
                              void* d_out, int out_size, void* d_ws, size_t ws_size,
                              hipStream_t stream) {
    const float* feat = (const float*)d_in[0];
    const int*   esrc = (const int*)d_in[1];
    const int*   edst = (const int*)d_in[2];
    const float* ew   = (const float*)d_in[3];
    const float* W1   = (const float*)d_in[4];
    const float* W2   = (const float*)d_in[5];
    const float* W_ih = (const float*)d_in[6];
    const float* W_hh = (const float*)d_in[7];
    const float* b_ih = (const float*)d_in[8];
    const float* b_hh = (const float*)d_in[9];
    float* out = (float*)d_out;

    // ws words: Ah 9.6M | off 100K | csr1 600K | csr2 600K | bsum 256
    //         | M1 49152 | M2 49152 | Bt 98304  (~44.4 MB)
    const size_t AH_ELEMS = (size_t)N_NODES * KTOT;  // u16 count
    const size_t needWords = AH_ELEMS / 2 + 2 * N_NODES + 2 * (size_t)N_EDGES
                           + 256 + 2 * (size_t)KTOT * D + (NCOLS * KTOT) / 2;
    if (ws_size < needWords * 4) {
        fill_sentinel<<<512, 256, 0, stream>>>(out, (long)out_size, 12345.0f);
        return;
    }

    u16*   Ah   = (u16*)d_ws;
    int*   off1 = (int*)(Ah + AH_ELEMS);
    int*   off2 = off1 + N_NODES;
    u32*   csr1 = (u32*)(off2 + N_NODES);
    u32*   csr2 = csr1 + N_EDGES;
    int*   bsum = (int*)(csr2 + N_EDGES);
    float* M1   = (float*)(bsum + 256);
    float* M2   = M1 + KTOT * D;
    u16*   Bt   = (u16*)(M2 + KTOT * D);

    const int EB = (N_EDGES + 255) / 256;

    convert_feat<<<(N_NODES * (D / 4) + 255) / 256, 256, 0, stream>>>(feat, Ah);

    zero_words<<<(2 * N_NODES + 255) / 256, 256, 0, stream>>>((u32*)off1, 2 * N_NODES);
    count_both<<<EB, 256, 0, stream>>>(esrc, edst, off1, off2);
    scan_partial<<<dim3(SCAN_NB, 2), 256, 0, stream>>>(off1, bsum);
    scan_bsums<<<1, 256, 0, stream>>>(bsum);
    scan_final<<<dim3(SCAN_NB, 2), 256, 0, stream>>>(off1, bsum);
    scatter_both<<<EB, 256, 0, stream>>>(esrc, edst, ew, off1, csr1, off2, csr2);
    gather_both<<<(2 * N_NODES * 64 + 255) / 256, 256, 0, stream>>>(
        Ah, off1, csr1, off2, csr2);

    compute_M<<<dim3(KTOT, 2), 128, 0, stream>>>(W_ih, W1, W2, M1, M2);
    fill_Bt<<<(NCOLS * KTOT + 255) / 256, 256, 0, stream>>>(M1, M2, W_hh, Bt);

    gemm_gru_mfma<<<GEMM_NWG, 256, 0, stream>>>(Ah, Bt, feat, b_ih, b_hh, out);
}

// Round 11
// 282.420 us; speedup vs baseline: 4.8058x; 1.1895x over previous
//
#include <hip/hip_runtime.h>
#include <math.h>

#define N_NODES 50000
#define N_EDGES 600000
#define D 128
#define KTOT 384    // 3*D  (k: [n1 | n2 | feat])
#define NCOLS 512   // 4*D  (gate-interleaved cols: c' = 4c+g)

#define SCAN_CHUNK 512
#define SCAN_NB ((N_NODES + SCAN_CHUNK - 1) / SCAN_CHUNK)   // 98

#define GEMM_ROWB ((N_NODES + 127) / 128)    // 391 row panels
#define GEMM_NWG  (GEMM_ROWB * 8)            // 3128 blocks, 8 col-blocks
#define NXCD 8

typedef unsigned int u32;
typedef unsigned short u16;

typedef __attribute__((ext_vector_type(8))) short bf16x8;   // 8 bf16 (4 VGPRs)
typedef __attribute__((ext_vector_type(4))) float f32x4;

__device__ __forceinline__ float b2f(u16 x) {
    u32 u = ((u32)x) << 16;
    float f; __builtin_memcpy(&f, &u, 4);
    return f;
}
__device__ __forceinline__ u16 f2b(float f) {   // RNE bf16
    u32 u; __builtin_memcpy(&u, &f, 4);
    u32 r = (u + 0x7fffu + ((u >> 16) & 1u)) >> 16;
    return (u16)r;
}

// ---------------------------------------------------------------------------
__global__ void zero_words(u32* __restrict__ p, long n) {
    long i = (long)blockIdx.x * blockDim.x + threadIdx.x;
    long stride = (long)gridDim.x * blockDim.x;
    for (; i < n; i += stride) p[i] = 0u;
}

__global__ void fill_sentinel(float* __restrict__ p, long n, float v) {
    long i = (long)blockIdx.x * blockDim.x + threadIdx.x;
    long stride = (long)gridDim.x * blockDim.x;
    for (; i < n; i += stride) p[i] = v;
}

// ---------------------------------------------------------------------------
// feat fp32 -> bf16 into Ah[:, 256:384]
// ---------------------------------------------------------------------------
__global__ void convert_feat(const float* __restrict__ feat, u16* __restrict__ Ah) {
    int i = blockIdx.x * blockDim.x + threadIdx.x;   // over N*D/4
    if (i >= N_NODES * (D / 4)) return;
    int n = i >> 5, j4 = i & 31;
    float4 v = *(const float4*)(feat + (size_t)n * D + j4 * 4);
    ushort4 o;
    o.x = f2b(v.x); o.y = f2b(v.y); o.z = f2b(v.z); o.w = f2b(v.w);
    *(ushort4*)(Ah + (size_t)n * KTOT + 256 + j4 * 4) = o;
}

// ---------------------------------------------------------------------------
// CSR build (both directions): count -> parallel 3-phase scan -> scatter.
// ---------------------------------------------------------------------------
__global__ void count_both(const int* __restrict__ esrc, const int* __restrict__ edst,
                           int* __restrict__ cnt1, int* __restrict__ cnt2) {
    int e = blockIdx.x * blockDim.x + threadIdx.x;
    if (e < N_EDGES) {
        atomicAdd(&cnt1[edst[e]], 1);
        atomicAdd(&cnt2[esrc[e]], 1);
    }
}

// Phase 1: per-block chunk sums. grid (SCAN_NB, 2), 256 threads, 2 elems/thread.
__global__ void scan_partial(const int* __restrict__ off, int* __restrict__ bsum) {
    int dir = blockIdx.y, bx = blockIdx.x, t = threadIdx.x;
    const int* a = off + (size_t)dir * N_NODES;
    int i0 = bx * SCAN_CHUNK + 2 * t;
    int s = 0;
    if (i0 < N_NODES) s += a[i0];
    if (i0 + 1 < N_NODES) s += a[i0 + 1];
    __shared__ int red[256];
    red[t] = s;
    __syncthreads();
    for (int d = 128; d > 0; d >>= 1) {
        if (t < d) red[t] += red[t + d];
        __syncthreads();
    }
    if (t == 0) bsum[dir * SCAN_NB + bx] = red[0];
}

// Phase 2: exclusive scan of the two bsum segments (one block, two halves).
__global__ void scan_bsums(int* __restrict__ bsum) {
    __shared__ int part[256];
    int t = threadIdx.x;
    int i = t & 127, dir = t >> 7;
    int v = (i < SCAN_NB) ? bsum[dir * SCAN_NB + i] : 0;
    part[t] = v;
    __syncthreads();
    for (int d = 1; d < 128; d <<= 1) {
        int add = (i >= d) ? part[t - d] : 0;
        __syncthreads();
        part[t] += add;
        __syncthreads();
    }
    if (i < SCAN_NB) bsum[dir * SCAN_NB + i] = part[t] - v;  // exclusive
}

// Phase 3: in-place exclusive scan of each chunk + block base.
__global__ void scan_final(int* __restrict__ off, const int* __restrict__ bsum) {
    int dir = blockIdx.y, bx = blockIdx.x, t = threadIdx.x;
    int* a = off + (size_t)dir * N_NODES;
    int base = bsum[dir * SCAN_NB + bx];
    int i0 = bx * SCAN_CHUNK + 2 * t;
    int e0 = (i0 < N_NODES) ? a[i0] : 0;
    int e1 = (i0 + 1 < N_NODES) ? a[i0 + 1] : 0;
    __shared__ int part[256];
    int v = e0 + e1;
    part[t] = v;
    __syncthreads();
    for (int d = 1; d < 256; d <<= 1) {
        int add = (t >= d) ? part[t - d] : 0;
        __syncthreads();
        part[t] += add;
        __syncthreads();
    }
    int tb = base + part[t] - v;   // exclusive prefix for this thread
    if (i0 < N_NODES) a[i0] = tb;
    if (i0 + 1 < N_NODES) a[i0 + 1] = tb + e0;
}

// Packed CSR entry: (nbr << 16) | bf16(w).  N_NODES < 2^16, w >= 0.
// After this kernel off[n] = end(n); start(n) = (n==0) ? 0 : off[n-1].
__global__ void scatter_both(const int* __restrict__ esrc, const int* __restrict__ edst,
                             const float* __restrict__ ew,
                             int* __restrict__ off1, u32* __restrict__ csr1,
                             int* __restrict__ off2, u32* __restrict__ csr2) {
    int e = blockIdx.x * blockDim.x + threadIdx.x;
    if (e < N_EDGES) {
        int s = esrc[e], d = edst[e];
        u32 wb = (u32)f2b(ew[e]);
        int p1 = atomicAdd(&off1[d], 1);
        csr1[p1] = ((u32)s << 16) | wb;
        int p2 = atomicAdd(&off2[s], 1);
        csr2[p2] = ((u32)d << 16) | wb;
    }
}

// ---------------------------------------------------------------------------
// Fused gather-aggregate, both directions. One wave per (node, dir); lane
// handles 2 features; 4-way unrolled (4 feature-row loads in flight).
// Writes mean into Ah[:,0:128]/[:,128:256].
// ---------------------------------------------------------------------------
__global__ void gather_both(u16* __restrict__ Ah,
                            const int* __restrict__ off1, const u32* __restrict__ csr1,
                            const int* __restrict__ off2, const u32* __restrict__ csr2) {
    int gw = (blockIdx.x * blockDim.x + threadIdx.x) >> 6;
    int lane = threadIdx.x & 63;
    if (gw >= 2 * N_NODES) return;
    int dir = (gw >= N_NODES);
    int n = dir ? gw - N_NODES : gw;
    const int* off = dir ? off2 : off1;
    const u32* csr = dir ? csr2 : csr1;
    int start = (n == 0) ? 0 : off[n - 1];
    int end = off[n];
    float ax = 0.f, ay = 0.f, sw = 0.f;
    int p = start;
    for (; p + 3 < end; p += 4) {
        u32 c0 = csr[p], c1 = csr[p + 1], c2 = csr[p + 2], c3 = csr[p + 3];
        u32 v0 = *(const u32*)(Ah + (size_t)(c0 >> 16) * KTOT + 256 + lane * 2);
        u32 v1 = *(const u32*)(Ah + (size_t)(c1 >> 16) * KTOT + 256 + lane * 2);
        u32 v2 = *(const u32*)(Ah + (size_t)(c2 >> 16) * KTOT + 256 + lane * 2);
        u32 v3 = *(const u32*)(Ah + (size_t)(c3 >> 16) * KTOT + 256 + lane * 2);
        float w0 = b2f((u16)c0), w1 = b2f((u16)c1);
        float w2 = b2f((u16)c2), w3 = b2f((u16)c3);
        ax += b2f((u16)v0) * w0 + b2f((u16)v1) * w1
            + b2f((u16)v2) * w2 + b2f((u16)v3) * w3;
        ay += b2f((u16)(v0 >> 16)) * w0 + b2f((u16)(v1 >> 16)) * w1
            + b2f((u16)(v2 >> 16)) * w2 + b2f((u16)(v3 >> 16)) * w3;
        sw += w0 + w1 + w2 + w3;
    }
    for (; p < end; ++p) {
        u32 c0 = csr[p];
        u32 v0 = *(const u32*)(Ah + (size_t)(c0 >> 16) * KTOT + 256 + lane * 2);
        float w0 = b2f((u16)c0);
        ax += b2f((u16)v0) * w0;
        ay += b2f((u16)(v0 >> 16)) * w0;
        sw += w0;
    }
    float inv = (sw > 0.f) ? 1.f / sw : 0.f;
    if (!isfinite(inv)) inv = 0.f;
    u32 o = ((u32)f2b(ay * inv) << 16) | (u32)f2b(ax * inv);
    *(u32*)(Ah + (size_t)n * KTOT + dir * 128 + lane * 2) = o;
}

// ---------------------------------------------------------------------------
// Weight folding: M1 = W_ih[:, :128] @ W1 ; M2 = W_ih[:, 128:] @ W2 (fp32).
// ---------------------------------------------------------------------------
__global__ void compute_M(const float* __restrict__ W_ih,
                          const float* __restrict__ W1,
                          const float* __restrict__ W2,
                          float* __restrict__ M1, float* __restrict__ M2) {
    int r = blockIdx.x;          // 0..383
    int k = threadIdx.x;         // 0..127
    int which = blockIdx.y;
    const float* Wsel = which ? W2 : W1;
    const float* ih = W_ih + (size_t)r * (2 * D) + which * D;
    float acc = 0.f;
    for (int j = 0; j < D; ++j) acc += ih[j] * Wsel[j * D + k];
    (which ? M2 : M1)[r * D + k] = acc;
}

// ---------------------------------------------------------------------------
// Bt [512 cols][384 k] bf16, k-contiguous rows. Col c' = 4c+g:
//   g=0: r-sum rows c (M1|M2|W_hh); g=1: z-sum rows c+128;
//   g=2: gi_n rows c+256 (M1|M2|0); g=3: gh_n (0|0|W_hh row c+256)
// ---------------------------------------------------------------------------
__global__ void fill_Bt(const float* __restrict__ M1, const float* __restrict__ M2,
                        const float* __restrict__ W_hh, u16* __restrict__ Bt) {
    int idx = blockIdx.x * blockDim.x + threadIdx.x;
    if (idx >= NCOLS * KTOT) return;
    int cp = idx / KTOT;
    int k  = idx - cp * KTOT;
    int c = cp >> 2, g = cp & 3;
    float v = 0.f;
    if (g <= 1) {
        int r = c + (g == 1 ? 128 : 0);
        v = (k < 128) ? M1[r * D + k]
          : (k < 256) ? M2[r * D + (k - 128)]
                      : W_hh[r * D + (k - 256)];
    } else if (g == 2) {
        int r = c + 256;
        v = (k < 128) ? M1[r * D + k]
          : (k < 256) ? M2[r * D + (k - 128)] : 0.f;
    } else {
        v = (k >= 256) ? W_hh[(c + 256) * D + (k - 256)] : 0.f;
    }
    if (!isfinite(v)) v = 0.f;
    Bt[idx] = f2b(v);
}

// ---------------------------------------------------------------------------
// MFMA GEMM + fused GRU, v5 (= v4 with the swizzle-composition bug fixed).
// Block 128x64 (4 waves of 32x64), XCD-swizzled 1D grid.
// B panel [64 cols][384 k] staged once in 48 KB LDS, XOR swizzle
// byte ^= (col&7)<<4 applied to the FULL byte offset on write AND on read
// (rule #21: same involution both sides; v4 XOR'd the base then added
// ks*64 after, which breaks carries into bit 6 and even ran 16B OOB).
// Depth-4 A-prefetch ring; epilogue LDS aliases the B buffer.
// ---------------------------------------------------------------------------
__global__ __launch_bounds__(256)
void gemm_gru_mfma(const u16* __restrict__ Ah, const u16* __restrict__ Bt,
                   const float* __restrict__ feat,
                   const float* __restrict__ b_ih, const float* __restrict__ b_hh,
                   float* __restrict__ out) {
    __shared__ __align__(16) char smem[64 * KTOT * 2];   // 48 KB: B panel / epi
    float (*epi)[16][65] = (float(*)[16][65])smem;       // aliases B (dead later)

    int bid = blockIdx.x;
    int wgid = (bid % NXCD) * (GEMM_NWG / NXCD) + bid / NXCD;   // bijective
    int rowp = wgid >> 3;
    int colb = wgid & 7;
    int tid = threadIdx.x, lane = tid & 63, wid = tid >> 6;
    int mw = rowp * 128 + wid * 32;         // wave row (node) base
    int nw = colb * 64;                     // block gate-col base (all waves)
    int rif = lane & 15, kg = lane >> 4;

    // ---- stage B panel [64][384] into LDS (each thread: 12 x b128) ----
    {
        int col = tid >> 2;            // 0..63
        int q = tid & 3;               // 0..3 -> k quarter (96 k)
        const u16* src = Bt + (size_t)(nw + col) * KTOT + q * 96;
        u32 dbase = col * (KTOT * 2) + q * 192;
        u32 dxor = (u32)((col & 7) << 4);
        #pragma unroll
        for (int i = 0; i < 12; ++i) {
            bf16x8 v = *(const bf16x8*)(src + i * 8);
            *(bf16x8*)(smem + ((dbase + i * 16) ^ dxor)) = v;
        }
    }

    f32x4 acc[2][4];
    #pragma unroll
    for (int m = 0; m < 2; ++m)
        #pragma unroll
        for (int n = 0; n < 4; ++n)
            acc[m][n] = (f32x4){0.f, 0.f, 0.f, 0.f};

    const u16* aP[2];
    #pragma unroll
    for (int m = 0; m < 2; ++m) {
        int arow = min(mw + m * 16 + rif, N_NODES - 1);
        aP[m] = Ah + (size_t)arow * KTOT + kg * 8;
    }

    // B read: col base + per-col xor; XOR applied to FULL offset in the loop.
    u32 bCol[4], bXor[4];
    #pragma unroll
    for (int n = 0; n < 4; ++n) {
        u32 col = n * 16 + rif;
        bCol[n] = col * (KTOT * 2) + kg * 16;
        bXor[n] = (col & 7) << 4;
    }

    // depth-4 A prefetch ring (fully unrolled -> static indices)
    bf16x8 abuf[4][2];
    #pragma unroll
    for (int s = 0; s < 3; ++s)
        #pragma unroll
        for (int m = 0; m < 2; ++m)
            abuf[s][m] = *(const bf16x8*)(aP[m] + s * 32);

    __syncthreads();   // B panel ready

    #pragma unroll
    for (int ks = 0; ks < KTOT / 32; ++ks) {
        if (ks + 3 < KTOT / 32) {
            #pragma unroll
            for (int m = 0; m < 2; ++m)
                abuf[(ks + 3) & 3][m] = *(const bf16x8*)(aP[m] + (ks + 3) * 32);
        }
        bf16x8 bfr[4];
        #pragma unroll
        for (int n = 0; n < 4; ++n)
            bfr[n] = *(const bf16x8*)(smem + ((bCol[n] + ks * 64) ^ bXor[n]));
        #pragma unroll
        for (int m = 0; m < 2; ++m)
            #pragma unroll
            for (int n = 0; n < 4; ++n)
                acc[m][n] = __builtin_amdgcn_mfma_f32_16x16x32_bf16(
                    abuf[ks & 3][m], bfr[n], acc[m][n], 0, 0, 0);
    }

    // ---- epilogue: de-interleave gates + GRU (epi aliases B; barrier fences) ----
    int rc0 = nw >> 2;          // wave real-col base (16 real cols)
    int erow = lane >> 2;       // 0..15
    int g4 = lane & 3;          // 4 real cols per lane
    int cbase = rc0 + g4 * 4;
    float4 bi_r = *(const float4*)(b_ih + cbase);
    float4 bh_r = *(const float4*)(b_hh + cbase);
    float4 bi_z = *(const float4*)(b_ih + cbase + 128);
    float4 bh_z = *(const float4*)(b_hh + cbase + 128);
    float4 bi_n = *(const float4*)(b_ih + cbase + 256);
    float4 bh_n = *(const float4*)(b_hh + cbase + 256);

    #pragma unroll
    for (int m = 0; m < 2; ++m) {
        __syncthreads();    // fence: B reads done (m=0) / prev epi reads done
        #pragma unroll
        for (int n = 0; n < 4; ++n)
            #pragma unroll
            for (int reg = 0; reg < 4; ++reg)
                epi[wid][kg * 4 + reg][n * 16 + rif] = acc[m][n][reg];
        __syncthreads();

        float4 q0 = *(const float4*)&epi[wid][erow][g4 * 16 + 0];
        float4 q1 = *(const float4*)&epi[wid][erow][g4 * 16 + 4];
        float4 q2 = *(const float4*)&epi[wid][erow][g4 * 16 + 8];
        float4 q3 = *(const float4*)&epi[wid][erow][g4 * 16 + 12];

        int node = mw + m * 16 + erow;
        if (node < N_NODES) {
            float4 f = *(const float4*)(feat + (size_t)node * D + cbase);
            float4 res;
            {
                float r = 1.f / (1.f + __expf(-(q0.x + bi_r.x + bh_r.x)));
                float z = 1.f / (1.f + __expf(-(q0.y + bi_z.x + bh_z.x)));
                float ng = tanhf(q0.z + bi_n.x + r * (q0.w + bh_n.x));
                res.x = (1.f - z) * ng + z * f.x;
            }
            {
                float r = 1.f / (1.f + __expf(-(q1.x + bi_r.y + bh_r.y)));
                float z = 1.f / (1.f + __expf(-(q1.y + bi_z.y + bh_z.y)));
                float ng = tanhf(q1.z + bi_n.y + r * (q1.w + bh_n.y));
                res.y = (1.f - z) * ng + z * f.y;
            }
            {
                float r = 1.f / (1.f + __expf(-(q2.x + bi_r.z + bh_r.z)));
                float z = 1.f / (1.f + __expf(-(q2.y + bi_z.z + bh_z.z)));
                float ng = tanhf(q2.z + bi_n.z + r * (q2.w + bh_n.z));
                res.z = (1.f - z) * ng + z * f.z;
            }
            {
                float r = 1.f / (1.f + __expf(-(q3.x + bi_r.w + bh_r.w)));
                float z = 1.f / (1.f + __expf(-(q3.y + bi_z.w + bh_z.w)));
                float ng = tanhf(q3.z + bi_n.w + r * (q3.w + bh_n.w));
                res.w = (1.f - z) * ng + z * f.w;
            }
            *(float4*)(out + (size_t)node * D + cbase) = res;
        }
    }
}

// ===========================================================================
extern "C" void kernel_launch(void* const* d_in, const int* in_sizes, int n_in,
                              void* d_out, int out_size, void* d_ws, size_t ws_size,
                              hipStream_t stream) {
    const float* feat = (const float*)d_in[0];
    const int*   esrc = (const int*)d_in[1];
    const int*   edst = (const int*)d_in[2];
    const float* ew   = (const float*)d_in[3];
    const float* W1   = (const float*)d_in[4];
    const float* W2   = (const float*)d_in[5];
    const float* W_ih = (const float*)d_in[6];
    const float* W_hh = (const float*)d_in[7];
    const float* b_ih = (const float*)d_in[8];
    const float* b_hh = (const float*)d_in[9];
    float* out = (float*)d_out;

    // ws words: Ah 9.6M | off 100K | csr1 600K | csr2 600K | bsum 256
    //         | M1 49152 | M2 49152 | Bt 98304  (~44.4 MB)
    const size_t AH_ELEMS = (size_t)N_NODES * KTOT;  // u16 count
    const size_t needWords = AH_ELEMS / 2 + 2 * N_NODES + 2 * (size_t)N_EDGES
                           + 256 + 2 * (size_t)KTOT * D + (NCOLS * KTOT) / 2;
    if (ws_size < needWords * 4) {
        fill_sentinel<<<512, 256, 0, stream>>>(out, (long)out_size, 12345.0f);
        return;
    }

    u16*   Ah   = (u16*)d_ws;
    int*   off1 = (int*)(Ah + AH_ELEMS);
    int*   off2 = off1 + N_NODES;
    u32*   csr1 = (u32*)(off2 + N_NODES);
    u32*   csr2 = csr1 + N_EDGES;
    int*   bsum = (int*)(csr2 + N_EDGES);
    float* M1   = (float*)(bsum + 256);
    float* M2   = M1 + KTOT * D;
    u16*   Bt   = (u16*)(M2 + KTOT * D);

    const int EB = (N_EDGES + 255) / 256;

    convert_feat<<<(N_NODES * (D / 4) + 255) / 256, 256, 0, stream>>>(feat, Ah);

    zero_words<<<(2 * N_NODES + 255) / 256, 256, 0, stream>>>((u32*)off1, 2 * N_NODES);
    count_both<<<EB, 256, 0, stream>>>(esrc, edst, off1, off2);
    scan_partial<<<dim3(SCAN_NB, 2), 256, 0, stream>>>(off1, bsum);
    scan_bsums<<<1, 256, 0, stream>>>(bsum);
    scan_final<<<dim3(SCAN_NB, 2), 256, 0, stream>>>(off1, bsum);
    scatter_both<<<EB, 256, 0, stream>>>(esrc, edst, ew, off1, csr1, off2, csr2);
    gather_both<<<(2 * N_NODES * 64 + 255) / 256, 256, 0, stream>>>(
        Ah, off1, csr1, off2, csr2);

    compute_M<<<dim3(KTOT, 2), 128, 0, stream>>>(W_ih, W1, W2, M1, M2);
    fill_Bt<<<(NCOLS * KTOT + 255) / 256, 256, 0, stream>>>(M1, M2, W_hh, Bt);

    gemm_gru_mfma<<<GEMM_NWG, 256, 0, stream>>>(Ah, Bt, feat, b_ih, b_hh, out);
}

// Round 12
// 264.410 us; speedup vs baseline: 5.1332x; 1.0681x over previous
//
#include <hip/hip_runtime.h>
#include <math.h>

#define N_NODES 50000
#define N_EDGES 600000
#define D 128
#define KTOT 384    // 3*D  (k: [n1 | n2 | feat])
#define NCOLS 512   // 4*D  (gate-interleaved cols: c' = 4c+g)

#define SCAN_CHUNK 512
#define SCAN_NB ((N_NODES + SCAN_CHUNK - 1) / SCAN_CHUNK)   // 98

#define GEMM_ROWB ((N_NODES + 127) / 128)    // 391 row panels
#define GEMM_NWG  (GEMM_ROWB * 8)            // 3128 blocks, 8 col-blocks
#define NXCD 8

// binned CSR build
#define BSHIFT 10
#define NBUCKETS ((N_NODES + (1 << BSHIFT) - 1) >> BSHIFT)   // 49
#define PA_NB 512
#define PA_CHUNK ((N_EDGES + PA_NB - 1) / PA_NB)             // 1172
#define PB_SPLIT 4

typedef unsigned int u32;
typedef unsigned short u16;

typedef __attribute__((ext_vector_type(8))) short bf16x8;   // 8 bf16 (4 VGPRs)
typedef __attribute__((ext_vector_type(4))) float f32x4;

__device__ __forceinline__ float b2f(u16 x) {
    u32 u = ((u32)x) << 16;
    float f; __builtin_memcpy(&f, &u, 4);
    return f;
}
__device__ __forceinline__ u16 f2b(float f) {   // RNE bf16
    u32 u; __builtin_memcpy(&u, &f, 4);
    u32 r = (u + 0x7fffu + ((u >> 16) & 1u)) >> 16;
    return (u16)r;
}

// ---------------------------------------------------------------------------
__global__ void zero_words(u32* __restrict__ p, long n) {
    long i = (long)blockIdx.x * blockDim.x + threadIdx.x;
    long stride = (long)gridDim.x * blockDim.x;
    for (; i < n; i += stride) p[i] = 0u;
}

__global__ void fill_sentinel(float* __restrict__ p, long n, float v) {
    long i = (long)blockIdx.x * blockDim.x + threadIdx.x;
    long stride = (long)gridDim.x * blockDim.x;
    for (; i < n; i += stride) p[i] = v;
}

// ---------------------------------------------------------------------------
// feat fp32 -> bf16 into Ah[:, 256:384]
// ---------------------------------------------------------------------------
__global__ void convert_feat(const float* __restrict__ feat, u16* __restrict__ Ah) {
    int i = blockIdx.x * blockDim.x + threadIdx.x;   // over N*D/4
    if (i >= N_NODES * (D / 4)) return;
    int n = i >> 5, j4 = i & 31;
    float4 v = *(const float4*)(feat + (size_t)n * D + j4 * 4);
    ushort4 o;
    o.x = f2b(v.x); o.y = f2b(v.y); o.z = f2b(v.z); o.w = f2b(v.w);
    *(ushort4*)(Ah + (size_t)n * KTOT + 256 + j4 * 4) = o;
}

// ---------------------------------------------------------------------------
// CSR build step 1: degree count (both directions).
// ---------------------------------------------------------------------------
__global__ void count_both(const int* __restrict__ esrc, const int* __restrict__ edst,
                           int* __restrict__ cnt1, int* __restrict__ cnt2) {
    int e = blockIdx.x * blockDim.x + threadIdx.x;
    if (e < N_EDGES) {
        atomicAdd(&cnt1[edst[e]], 1);
        atomicAdd(&cnt2[esrc[e]], 1);
    }
}

// Phase 1: per-block chunk sums. grid (SCAN_NB, 2), 256 threads, 2 elems/thread.
__global__ void scan_partial(const int* __restrict__ off, int* __restrict__ bsum) {
    int dir = blockIdx.y, bx = blockIdx.x, t = threadIdx.x;
    const int* a = off + (size_t)dir * N_NODES;
    int i0 = bx * SCAN_CHUNK + 2 * t;
    int s = 0;
    if (i0 < N_NODES) s += a[i0];
    if (i0 + 1 < N_NODES) s += a[i0 + 1];
    __shared__ int red[256];
    red[t] = s;
    __syncthreads();
    for (int d = 128; d > 0; d >>= 1) {
        if (t < d) red[t] += red[t + d];
        __syncthreads();
    }
    if (t == 0) bsum[dir * SCAN_NB + bx] = red[0];
}

// Phase 2: exclusive scan of the two bsum segments (one block, two halves).
__global__ void scan_bsums(int* __restrict__ bsum) {
    __shared__ int part[256];
    int t = threadIdx.x;
    int i = t & 127, dir = t >> 7;
    int v = (i < SCAN_NB) ? bsum[dir * SCAN_NB + i] : 0;
    part[t] = v;
    __syncthreads();
    for (int d = 1; d < 128; d <<= 1) {
        int add = (i >= d) ? part[t - d] : 0;
        __syncthreads();
        part[t] += add;
        __syncthreads();
    }
    if (i < SCAN_NB) bsum[dir * SCAN_NB + i] = part[t] - v;  // exclusive
}

// Phase 3: in-place exclusive scan of each chunk + block base -> off[n]=start(n).
__global__ void scan_final(int* __restrict__ off, const int* __restrict__ bsum) {
    int dir = blockIdx.y, bx = blockIdx.x, t = threadIdx.x;
    int* a = off + (size_t)dir * N_NODES;
    int base = bsum[dir * SCAN_NB + bx];
    int i0 = bx * SCAN_CHUNK + 2 * t;
    int e0 = (i0 < N_NODES) ? a[i0] : 0;
    int e1 = (i0 + 1 < N_NODES) ? a[i0 + 1] : 0;
    __shared__ int part[256];
    int v = e0 + e1;
    part[t] = v;
    __syncthreads();
    for (int d = 1; d < 256; d <<= 1) {
        int add = (t >= d) ? part[t - d] : 0;
        __syncthreads();
        part[t] += add;
        __syncthreads();
    }
    int tb = base + part[t] - v;   // exclusive prefix for this thread
    if (i0 < N_NODES) a[i0] = tb;
    if (i0 + 1 < N_NODES) a[i0 + 1] = tb + e0;
}

// ---------------------------------------------------------------------------
// Bucket bounds for the binned build (read off starts BEFORE consumption).
// bucketStart[d][b] = CSR start of bucket b; bucketFill = working copy.
// ---------------------------------------------------------------------------
__global__ void init_buckets(const int* __restrict__ off1, const int* __restrict__ off2,
                             int* __restrict__ bks) {
    // layout: bks[0..49]=start1, [64..112]=fill1, [128..177]=start2, [192..240]=fill2
    int t = threadIdx.x;
    if (t <= NBUCKETS) {
        int n = t << BSHIFT;
        int s1 = (t == NBUCKETS) ? N_EDGES : off1[n];
        int s2 = (t == NBUCKETS) ? N_EDGES : off2[n];
        bks[t] = s1;
        bks[128 + t] = s2;
        if (t < NBUCKETS) { bks[64 + t] = s1; bks[192 + t] = s2; }
    }
}

// ---------------------------------------------------------------------------
// Phase A: partition edges into NBUCKETS coarse buckets (key>>BSHIFT) via
// LDS histogram + staging; flush contiguous per-bucket runs to tmp at
// offsets reserved from bucketFill. tmp entry: {key<<16|nbr, wbits}.
// ---------------------------------------------------------------------------
__global__ __launch_bounds__(256)
void partA(const int* __restrict__ key, const int* __restrict__ nbr,
           const float* __restrict__ ew, int* __restrict__ bucketFill,
           uint2* __restrict__ tmp) {
    __shared__ int lcnt[NBUCKETS];
    __shared__ int lbase[NBUCKETS + 1];
    __shared__ int gbase[NBUCKETS];
    __shared__ uint2 stage[PA_CHUNK];
    int t = threadIdx.x;
    int e0 = blockIdx.x * PA_CHUNK;
    int e1 = min(e0 + PA_CHUNK, N_EDGES);
    if (t < NBUCKETS) lcnt[t] = 0;
    __syncthreads();
    for (int e = e0 + t; e < e1; e += 256)
        atomicAdd(&lcnt[key[e] >> BSHIFT], 1);
    __syncthreads();
    if (t == 0) {
        int s = 0;
        for (int b = 0; b < NBUCKETS; ++b) { lbase[b] = s; s += lcnt[b]; }
        lbase[NBUCKETS] = s;
    }
    __syncthreads();
    if (t < NBUCKETS) {
        gbase[t] = atomicAdd(&bucketFill[t], lcnt[t]);
        lcnt[t] = 0;    // reuse as fill
    }
    __syncthreads();
    for (int e = e0 + t; e < e1; e += 256) {
        int k = key[e];
        int b = k >> BSHIFT;
        int i = lbase[b] + atomicAdd(&lcnt[b], 1);
        u32 wb = (u32)f2b(ew[e]);
        stage[i] = make_uint2(((u32)k << 16) | (u32)nbr[e], wb);
    }
    __syncthreads();
    int total = lbase[NBUCKETS];
    for (int i = t; i < total; i += 256) {
        int lo = 0, hi = NBUCKETS;           // find bucket: lbase[lo] <= i < lbase[lo+1]
        while (hi - lo > 1) { int mid = (lo + hi) >> 1; if (lbase[mid] <= i) lo = mid; else hi = mid; }
        tmp[gbase[lo] + (i - lbase[lo])] = stage[i];
    }
}

// ---------------------------------------------------------------------------
// Phase B: per-bucket exact scatter. Targets span only ~48 KB per bucket ->
// dirty lines combine in L2, ~1x write amplification. off consumed -> ends.
// ---------------------------------------------------------------------------
__global__ __launch_bounds__(256)
void partB(const uint2* __restrict__ tmp, const int* __restrict__ bucketStart,
           int* __restrict__ off, u32* __restrict__ csr) {
    int b = blockIdx.x;
    int s = bucketStart[b], e = bucketStart[b + 1];
    int cnt = e - s;
    int per = (cnt + PB_SPLIT - 1) / PB_SPLIT;
    int ss = s + blockIdx.y * per;
    int ee = min(ss + per, e);
    for (int i = ss + (int)threadIdx.x; i < ee; i += 256) {
        uint2 v = tmp[i];
        int dst = v.x >> 16;
        int p = atomicAdd(&off[dst], 1);
        csr[p] = ((v.x & 0xffffu) << 16) | v.y;
    }
}

// ---------------------------------------------------------------------------
// Fused gather-aggregate, both directions. One wave per (node, dir); lane
// handles 2 features; 4-way unrolled. Writes mean into Ah[:,0:128]/[:,128:256].
// ---------------------------------------------------------------------------
__global__ void gather_both(u16* __restrict__ Ah,
                            const int* __restrict__ off1, const u32* __restrict__ csr1,
                            const int* __restrict__ off2, const u32* __restrict__ csr2) {
    int gw = (blockIdx.x * blockDim.x + threadIdx.x) >> 6;
    int lane = threadIdx.x & 63;
    if (gw >= 2 * N_NODES) return;
    int dir = (gw >= N_NODES);
    int n = dir ? gw - N_NODES : gw;
    const int* off = dir ? off2 : off1;
    const u32* csr = dir ? csr2 : csr1;
    int start = (n == 0) ? 0 : off[n - 1];
    int end = off[n];
    float ax = 0.f, ay = 0.f, sw = 0.f;
    int p = start;
    for (; p + 3 < end; p += 4) {
        u32 c0 = csr[p], c1 = csr[p + 1], c2 = csr[p + 2], c3 = csr[p + 3];
        u32 v0 = *(const u32*)(Ah + (size_t)(c0 >> 16) * KTOT + 256 + lane * 2);
        u32 v1 = *(const u32*)(Ah + (size_t)(c1 >> 16) * KTOT + 256 + lane * 2);
        u32 v2 = *(const u32*)(Ah + (size_t)(c2 >> 16) * KTOT + 256 + lane * 2);
        u32 v3 = *(const u32*)(Ah + (size_t)(c3 >> 16) * KTOT + 256 + lane * 2);
        float w0 = b2f((u16)c0), w1 = b2f((u16)c1);
        float w2 = b2f((u16)c2), w3 = b2f((u16)c3);
        ax += b2f((u16)v0) * w0 + b2f((u16)v1) * w1
            + b2f((u16)v2) * w2 + b2f((u16)v3) * w3;
        ay += b2f((u16)(v0 >> 16)) * w0 + b2f((u16)(v1 >> 16)) * w1
            + b2f((u16)(v2 >> 16)) * w2 + b2f((u16)(v3 >> 16)) * w3;
        sw += w0 + w1 + w2 + w3;
    }
    for (; p < end; ++p) {
        u32 c0 = csr[p];
        u32 v0 = *(const u32*)(Ah + (size_t)(c0 >> 16) * KTOT + 256 + lane * 2);
        float w0 = b2f((u16)c0);
        ax += b2f((u16)v0) * w0;
        ay += b2f((u16)(v0 >> 16)) * w0;
        sw += w0;
    }
    float inv = (sw > 0.f) ? 1.f / sw : 0.f;
    if (!isfinite(inv)) inv = 0.f;
    u32 o = ((u32)f2b(ay * inv) << 16) | (u32)f2b(ax * inv);
    *(u32*)(Ah + (size_t)n * KTOT + dir * 128 + lane * 2) = o;
}

// ---------------------------------------------------------------------------
// Weight folding: M1 = W_ih[:, :128] @ W1 ; M2 = W_ih[:, 128:] @ W2 (fp32).
// ---------------------------------------------------------------------------
__global__ void compute_M(const float* __restrict__ W_ih,
                          const float* __restrict__ W1,
                          const float* __restrict__ W2,
                          float* __restrict__ M1, float* __restrict__ M2) {
    int r = blockIdx.x;          // 0..383
    int k = threadIdx.x;         // 0..127
    int which = blockIdx.y;
    const float* Wsel = which ? W2 : W1;
    const float* ih = W_ih + (size_t)r * (2 * D) + which * D;
    float acc = 0.f;
    for (int j = 0; j < D; ++j) acc += ih[j] * Wsel[j * D + k];
    (which ? M2 : M1)[r * D + k] = acc;
}

// ---------------------------------------------------------------------------
// Bt [512 cols][384 k] bf16, k-contiguous rows. Col c' = 4c+g:
//   g=0: r-sum rows c (M1|M2|W_hh); g=1: z-sum rows c+128;
//   g=2: gi_n rows c+256 (M1|M2|0); g=3: gh_n (0|0|W_hh row c+256)
// ---------------------------------------------------------------------------
__global__ void fill_Bt(const float* __restrict__ M1, const float* __restrict__ M2,
                        const float* __restrict__ W_hh, u16* __restrict__ Bt) {
    int idx = blockIdx.x * blockDim.x + threadIdx.x;
    if (idx >= NCOLS * KTOT) return;
    int cp = idx / KTOT;
    int k  = idx - cp * KTOT;
    int c = cp >> 2, g = cp & 3;
    float v = 0.f;
    if (g <= 1) {
        int r = c + (g == 1 ? 128 : 0);
        v = (k < 128) ? M1[r * D + k]
          : (k < 256) ? M2[r * D + (k - 128)]
                      : W_hh[r * D + (k - 256)];
    } else if (g == 2) {
        int r = c + 256;
        v = (k < 128) ? M1[r * D + k]
          : (k < 256) ? M2[r * D + (k - 128)] : 0.f;
    } else {
        v = (k >= 256) ? W_hh[(c + 256) * D + (k - 256)] : 0.f;
    }
    if (!isfinite(v)) v = 0.f;
    Bt[idx] = f2b(v);
}

// ---------------------------------------------------------------------------
// MFMA GEMM + fused GRU, v5 (round-11 verified). Block 128x64 (4 waves of
// 32x64), XCD-swizzled 1D grid; B panel in 48 KB LDS with XOR swizzle applied
// to FULL offset both sides; depth-4 A-prefetch ring; epilogue aliases B LDS.
// ---------------------------------------------------------------------------
__global__ __launch_bounds__(256)
void gemm_gru_mfma(const u16* __restrict__ Ah, const u16* __restrict__ Bt,
                   const float* __restrict__ feat,
                   const float* __restrict__ b_ih, const float* __restrict__ b_hh,
                   float* __restrict__ out) {
    __shared__ __align__(16) char smem[64 * KTOT * 2];   // 48 KB: B panel / epi
    float (*epi)[16][65] = (float(*)[16][65])smem;       // aliases B (dead later)

    int bid = blockIdx.x;
    int wgid = (bid % NXCD) * (GEMM_NWG / NXCD) + bid / NXCD;   // bijective
    int rowp = wgid >> 3;
    int colb = wgid & 7;
    int tid = threadIdx.x, lane = tid & 63, wid = tid >> 6;
    int mw = rowp * 128 + wid * 32;         // wave row (node) base
    int nw = colb * 64;                     // block gate-col base (all waves)
    int rif = lane & 15, kg = lane >> 4;

    // ---- stage B panel [64][384] into LDS (each thread: 12 x b128) ----
    {
        int col = tid >> 2;            // 0..63
        int q = tid & 3;               // 0..3 -> k quarter (96 k)
        const u16* src = Bt + (size_t)(nw + col) * KTOT + q * 96;
        u32 dbase = col * (KTOT * 2) + q * 192;
        u32 dxor = (u32)((col & 7) << 4);
        #pragma unroll
        for (int i = 0; i < 12; ++i) {
            bf16x8 v = *(const bf16x8*)(src + i * 8);
            *(bf16x8*)(smem + ((dbase + i * 16) ^ dxor)) = v;
        }
    }

    f32x4 acc[2][4];
    #pragma unroll
    for (int m = 0; m < 2; ++m)
        #pragma unroll
        for (int n = 0; n < 4; ++n)
            acc[m][n] = (f32x4){0.f, 0.f, 0.f, 0.f};

    const u16* aP[2];
    #pragma unroll
    for (int m = 0; m < 2; ++m) {
        int arow = min(mw + m * 16 + rif, N_NODES - 1);
        aP[m] = Ah + (size_t)arow * KTOT + kg * 8;
    }

    // B read: col base; XOR applied to FULL offset in the loop (rule #21).
    u32 bCol[4], bXor[4];
    #pragma unroll
    for (int n = 0; n < 4; ++n) {
        u32 col = n * 16 + rif;
        bCol[n] = col * (KTOT * 2) + kg * 16;
        bXor[n] = (col & 7) << 4;
    }

    // depth-4 A prefetch ring (fully unrolled -> static indices)
    bf16x8 abuf[4][2];
    #pragma unroll
    for (int s = 0; s < 3; ++s)
        #pragma unroll
        for (int m = 0; m < 2; ++m)
            abuf[s][m] = *(const bf16x8*)(aP[m] + s * 32);

    __syncthreads();   // B panel ready

    #pragma unroll
    for (int ks = 0; ks < KTOT / 32; ++ks) {
        if (ks + 3 < KTOT / 32) {
            #pragma unroll
            for (int m = 0; m < 2; ++m)
                abuf[(ks + 3) & 3][m] = *(const bf16x8*)(aP[m] + (ks + 3) * 32);
        }
        bf16x8 bfr[4];
        #pragma unroll
        for (int n = 0; n < 4; ++n)
            bfr[n] = *(const bf16x8*)(smem + ((bCol[n] + ks * 64) ^ bXor[n]));
        #pragma unroll
        for (int m = 0; m < 2; ++m)
            #pragma unroll
            for (int n = 0; n < 4; ++n)
                acc[m][n] = __builtin_amdgcn_mfma_f32_16x16x32_bf16(
                    abuf[ks & 3][m], bfr[n], acc[m][n], 0, 0, 0);
    }

    // ---- epilogue: de-interleave gates + GRU (epi aliases B; barrier fences) ----
    int rc0 = nw >> 2;          // wave real-col base (16 real cols)
    int erow = lane >> 2;       // 0..15
    int g4 = lane & 3;          // 4 real cols per lane
    int cbase = rc0 + g4 * 4;
    float4 bi_r = *(const float4*)(b_ih + cbase);
    float4 bh_r = *(const float4*)(b_hh + cbase);
    float4 bi_z = *(const float4*)(b_ih + cbase + 128);
    float4 bh_z = *(const float4*)(b_hh + cbase + 128);
    float4 bi_n = *(const float4*)(b_ih + cbase + 256);
    float4 bh_n = *(const float4*)(b_hh + cbase + 256);

    #pragma unroll
    for (int m = 0; m < 2; ++m) {
        __syncthreads();    // fence: B reads done (m=0) / prev epi reads done
        #pragma unroll
        for (int n = 0; n < 4; ++n)
            #pragma unroll
            for (int reg = 0; reg < 4; ++reg)
                epi[wid][kg * 4 + reg][n * 16 + rif] = acc[m][n][reg];
        __syncthreads();

        float4 q0 = *(const float4*)&epi[wid][erow][g4 * 16 + 0];
        float4 q1 = *(const float4*)&epi[wid][erow][g4 * 16 + 4];
        float4 q2 = *(const float4*)&epi[wid][erow][g4 * 16 + 8];
        float4 q3 = *(const float4*)&epi[wid][erow][g4 * 16 + 12];

        int node = mw + m * 16 + erow;
        if (node < N_NODES) {
            float4 f = *(const float4*)(feat + (size_t)node * D + cbase);
            float4 res;
            {
                float r = 1.f / (1.f + __expf(-(q0.x + bi_r.x + bh_r.x)));
                float z = 1.f / (1.f + __expf(-(q0.y + bi_z.x + bh_z.x)));
                float ng = tanhf(q0.z + bi_n.x + r * (q0.w + bh_n.x));
                res.x = (1.f - z) * ng + z * f.x;
            }
            {
                float r = 1.f / (1.f + __expf(-(q1.x + bi_r.y + bh_r.y)));
                float z = 1.f / (1.f + __expf(-(q1.y + bi_z.y + bh_z.y)));
                float ng = tanhf(q1.z + bi_n.y + r * (q1.w + bh_n.y));
                res.y = (1.f - z) * ng + z * f.y;
            }
            {
                float r = 1.f / (1.f + __expf(-(q2.x + bi_r.z + bh_r.z)));
                float z = 1.f / (1.f + __expf(-(q2.y + bi_z.z + bh_z.z)));
                float ng = tanhf(q2.z + bi_n.z + r * (q2.w + bh_n.z));
                res.z = (1.f - z) * ng + z * f.z;
            }
            {
                float r = 1.f / (1.f + __expf(-(q3.x + bi_r.w + bh_r.w)));
                float z = 1.f / (1.f + __expf(-(q3.y + bi_z.w + bh_z.w)));
                float ng = tanhf(q3.z + bi_n.w + r * (q3.w + bh_n.w));
                res.w = (1.f - z) * ng + z * f.w;
            }
            *(float4*)(out + (size_t)node * D + cbase) = res;
        }
    }
}

// ===========================================================================
extern "C" void kernel_launch(void* const* d_in, const int* in_sizes, int n_in,
                              void* d_out, int out_size, void* d_ws, size_t ws_size,
                              hipStream_t stream) {
    const float* feat = (const float*)d_in[0];
    const int*   esrc = (const int*)d_in[1];
    const int*   edst = (const int*)d_in[2];
    const float* ew   = (const float*)d_in[3];
    const float* W1   = (const float*)d_in[4];
    const float* W2   = (const float*)d_in[5];
    const float* W_ih = (const float*)d_in[6];
    const float* W_hh = (const float*)d_in[7];
    const float* b_ih = (const float*)d_in[8];
    const float* b_hh = (const float*)d_in[9];
    float* out = (float*)d_out;

    // ws words: Ah 9.6M | off 100K | csr1 600K | csr2 600K | tmp 1.2M
    //         | bsum 256 | buckets 256 | M1 49152 | M2 49152 | Bt 98304  (~49.4 MB)
    const size_t AH_ELEMS = (size_t)N_NODES * KTOT;  // u16 count
    const size_t needWords = AH_ELEMS / 2 + 2 * N_NODES + 2 * (size_t)N_EDGES
                           + 2 * (size_t)N_EDGES          // tmp (uint2)
                           + 512 + 2 * (size_t)KTOT * D + (NCOLS * KTOT) / 2;
    if (ws_size < needWords * 4) {
        fill_sentinel<<<512, 256, 0, stream>>>(out, (long)out_size, 12345.0f);
        return;
    }

    u16*   Ah   = (u16*)d_ws;
    int*   off1 = (int*)(Ah + AH_ELEMS);
    int*   off2 = off1 + N_NODES;
    u32*   csr1 = (u32*)(off2 + N_NODES);
    u32*   csr2 = csr1 + N_EDGES;
    uint2* tmp  = (uint2*)(csr2 + N_EDGES);
    int*   bsum = (int*)(tmp + N_EDGES);
    int*   bks  = bsum + 256;          // bucketStart1/fill1/start2/fill2 (4x64)
    float* M1   = (float*)(bks + 256);
    float* M2   = M1 + KTOT * D;
    u16*   Bt   = (u16*)(M2 + KTOT * D);

    const int EB = (N_EDGES + 255) / 256;

    convert_feat<<<(N_NODES * (D / 4) + 255) / 256, 256, 0, stream>>>(feat, Ah);

    zero_words<<<(2 * N_NODES + 255) / 256, 256, 0, stream>>>((u32*)off1, 2 * N_NODES);
    count_both<<<EB, 256, 0, stream>>>(esrc, edst, off1, off2);
    scan_partial<<<dim3(SCAN_NB, 2), 256, 0, stream>>>(off1, bsum);
    scan_bsums<<<1, 256, 0, stream>>>(bsum);
    scan_final<<<dim3(SCAN_NB, 2), 256, 0, stream>>>(off1, bsum);

    init_buckets<<<1, 64, 0, stream>>>(off1, off2, bks);
    // dir 1: key = dst, nbr = src
    partA<<<PA_NB, 256, 0, stream>>>(edst, esrc, ew, bks + 64, tmp);
    partB<<<dim3(NBUCKETS, PB_SPLIT), 256, 0, stream>>>(tmp, bks, off1, csr1);
    // dir 2: key = src, nbr = dst
    partA<<<PA_NB, 256, 0, stream>>>(esrc, edst, ew, bks + 192, tmp);
    partB<<<dim3(NBUCKETS, PB_SPLIT), 256, 0, stream>>>(tmp, bks + 128, off2, csr2);

    gather_both<<<(2 * N_NODES * 64 + 255) / 256, 256, 0, stream>>>(
        Ah, off1, csr1, off2, csr2);

    compute_M<<<dim3(KTOT, 2), 128, 0, stream>>>(W_ih, W1, W2, M1, M2);
    fill_Bt<<<(NCOLS * KTOT + 255) / 256, 256, 0, stream>>>(M1, M2, W_hh, Bt);

    gemm_gru_mfma<<<GEMM_NWG, 256, 0, stream>>>(Ah, Bt, feat, b_ih, b_hh, out);
}